// Round 9
// baseline (565.309 us; speedup 1.0000x reference)
//
#include <hip/hip_runtime.h>
#include <math.h>

#define B_ 16
#define J_ 96
#define I_ 96
#define E_ 256
#define H_ 512
#define VS_ 32000
#define SJ_ 193
#define NROW (B_*J_)   // 1536

typedef __attribute__((ext_vector_type(8))) short short8;
typedef __attribute__((ext_vector_type(4))) float f32x4;
typedef __attribute__((ext_vector_type(4))) unsigned int u32x4;

__device__ __forceinline__ float sigf(float x){ return 1.f/(1.f+__expf(-x)); }

__device__ __forceinline__ unsigned short f2bf(float x){
  unsigned int u = __float_as_uint(x);
  unsigned int r = (u + 0x7FFFu + ((u>>16)&1u)) >> 16;
  return (unsigned short)r;
}

#define ASYNC16(gp, lp) __builtin_amdgcn_global_load_lds( \
    (const __attribute__((address_space(1))) unsigned int*)(gp), \
    (__attribute__((address_space(3))) unsigned int*)(lp), 16, 0, 0)

// 256-thr transpose+convert: src fp32 [K][ld] -> dst bf16 [N][K], zero-pad n>=nmax
__device__ __forceinline__ void wtr_tile256(const float* __restrict__ src,
                                            unsigned short* __restrict__ dst,
                                            int ldN, int nmax, int K, int n0, int k0,
                                            float* __restrict__ tile /*[64][65]*/)
{
  const int t = threadIdx.x;
  #pragma unroll
  for (int rep = 0; rep < 16; rep++){
    int idx = rep*256 + t;
    int kk = idx >> 6, nn = idx & 63;
    tile[kk*65 + nn] = (n0+nn < nmax) ? src[(long long)(k0+kk)*ldN + n0 + nn] : 0.f;
  }
  __syncthreads();
  #pragma unroll
  for (int rep = 0; rep < 16; rep++){
    int idx = rep*256 + t;
    int nn = idx >> 6, kk = idx & 63;
    dst[(long long)(n0+nn)*K + k0 + kk] = f2bf(tile[kk*65 + nn]);
  }
}

// 512-thr version (used in k_fused side tasks)
__device__ __forceinline__ void wtr_tile(const float* __restrict__ src,
                                         unsigned short* __restrict__ dst,
                                         int ldN, int nmax, int K, int n0, int k0,
                                         float* __restrict__ tile)
{
  const int t = threadIdx.x;
  #pragma unroll
  for (int rep = 0; rep < 8; rep++){
    int idx = rep*512 + t;
    int kk = idx >> 6, nn = idx & 63;
    tile[kk*65 + nn] = (n0+nn < nmax) ? src[(long long)(k0+kk)*ldN + n0 + nn] : 0.f;
  }
  __syncthreads();
  #pragma unroll
  for (int rep = 0; rep < 8; rep++){
    int idx = rep*512 + t;
    int nn = idx >> 6, kk = idx & 63;
    dst[(long long)(n0+nn)*K + k0 + kk] = f2bf(tile[kk*65 + nn]);
  }
}

// ---------------------------------------------------------------------------
// Head: init hex/rowsum, embed->bf16, Wfw/Wbw transpose, bias copy. One launch.
// grid = 1536(embed) + 256(wtr) + 128(hex0) + 7(rowsum0) + 16(biascopy) = 1943
// ---------------------------------------------------------------------------
__global__ __launch_bounds__(256) void k_head(
    const int* __restrict__ targets, const float* __restrict__ emb,
    unsigned short* __restrict__ e_word_h,
    const float* __restrict__ Wfw, const float* __restrict__ Wbw,
    unsigned short* __restrict__ WT,
    unsigned int* __restrict__ hex, float* __restrict__ rowsum,
    const float* __restrict__ bfw, const float* __restrict__ bbw,
    float* __restrict__ wsb)
{
  __shared__ float tile[64*65];
  int bid = blockIdx.x;
  const int t = threadIdx.x;
  if (bid < 1536){
    int tr = targets[bid];
    e_word_h[(long long)bid*E_ + t] = f2bf(emb[(long long)tr*E_ + t]);
    return;
  }
  bid -= 1536;
  if (bid < 256){
    int y = bid >> 7;
    const float* src = y ? Wbw : Wfw;
    unsigned short* dst = WT + (long long)y*2048*256;
    int sid = bid & 127;
    wtr_tile256(src, dst, 2048, 2048, 256, (sid & 31)*64, (sid >> 5)*64, tile);
    return;
  }
  bid -= 256;
  if (bid < 128){ hex[bid*256 + t] = 0u; return; }
  bid -= 128;
  if (bid < 7){
    int i = bid*256 + t;
    if (i < NROW + 1) rowsum[i] = 0.f;
    return;
  }
  bid -= 7;
  int i = bid*256 + t;                       // 16 blocks, 4096 floats
  wsb[i] = (i < 2048) ? bfw[i] : bbw[i - 2048];
}

// ---------------------------------------------------------------------------
// 128x128 bf16 MFMA K-loop (shared by k_bgemm and k_mega)
// ---------------------------------------------------------------------------
__device__ __forceinline__ void gemm128(const unsigned short* __restrict__ Ah,
                                        const unsigned short* __restrict__ Bh,
                                        int K, int m0, int n0,
                                        unsigned short* As, unsigned short* Bs,
                                        f32x4 (&acc)[4][4])
{
  const int t = threadIdx.x;
  const int lane = t & 63, w = t >> 6;
  const int wm = (w >> 1)*64, wn = (w & 1)*64;
  for (int k0 = 0; k0 < K; k0 += 32){
    #pragma unroll
    for (int p = 0; p < 2; p++){
      int rowA = p*64 + (t >> 2);
      int kc = (t & 3) ^ ((rowA >> 1) & 3);
      const unsigned short* ga = Ah + (long long)(m0 + rowA)*K + k0 + kc*8;
      const unsigned short* gb = Bh + (long long)(n0 + rowA)*K + k0 + kc*8;
      unsigned short* la = As + p*2048 + w*512;
      unsigned short* lb = Bs + p*2048 + w*512;
      ASYNC16(ga, la);
      ASYNC16(gb, lb);
    }
    __syncthreads();
    short8 af[4], bf[4];
    const int rr = lane & 15, kch = lane >> 4;
    #pragma unroll
    for (int mi = 0; mi < 4; mi++){
      int rowA = wm + mi*16 + rr;
      int slot = kch ^ ((rowA >> 1) & 3);
      af[mi] = *(const short8*)&As[rowA*32 + slot*8];
    }
    #pragma unroll
    for (int ni = 0; ni < 4; ni++){
      int rowB = wn + ni*16 + rr;
      int slot = kch ^ ((rowB >> 1) & 3);
      bf[ni] = *(const short8*)&Bs[rowB*32 + slot*8];
    }
    #pragma unroll
    for (int mi = 0; mi < 4; mi++)
      #pragma unroll
      for (int ni = 0; ni < 4; ni++)
        acc[mi][ni] = __builtin_amdgcn_mfma_f32_16x16x32_bf16(af[mi], bf[ni], acc[mi][ni], 0, 0, 0);
    __syncthreads();
  }
}

// Generic bf16 MFMA GEMM (BT layout). MODE 0: Cf=acc+bias; MODE 2: Ch=bf16(tanh(acc+bias)).
// gridDim.y==2 applies sB2/sBias2/sC2 to the second slice (dual-launch).
template<int MODE>
__global__ __launch_bounds__(256, 2) void k_bgemm(
    const unsigned short* __restrict__ Ah,
    const unsigned short* __restrict__ Bh,
    int K, int ncols,
    const float* __restrict__ bias,
    float* __restrict__ Cf,
    unsigned short* __restrict__ Ch,
    int ldc,
    long long sB2, long long sBias2, long long sC2)
{
  __shared__ unsigned short As[128*32];
  __shared__ unsigned short Bs[128*32];
  if (blockIdx.y){
    Bh += sB2;
    if (bias) bias += sBias2;
    if (Cf) Cf += sC2;
    if (Ch) Ch += sC2;
  }
  int nwg = gridDim.x;
  int braw = blockIdx.x;
  int wg = (braw & 7)*(nwg >> 3) + (braw >> 3);   // bijective: nwg % 8 == 0
  int mt = wg % 12, nt = wg / 12;
  const int m0 = mt*128, n0 = nt*128;
  f32x4 acc[4][4] = {};
  gemm128(Ah, Bh, K, m0, n0, As, Bs, acc);
  const int t = threadIdx.x;
  const int lane = t & 63, w = t >> 6;
  const int wm = (w >> 1)*64, wn = (w & 1)*64;
  #pragma unroll
  for (int mi = 0; mi < 4; mi++){
    #pragma unroll
    for (int r = 0; r < 4; r++){
      int row = m0 + wm + mi*16 + ((lane >> 4) << 2) + r;
      #pragma unroll
      for (int ni = 0; ni < 4; ni++){
        int col = n0 + wn + ni*16 + (lane & 15);
        if (col >= ncols) continue;
        float v = acc[mi][ni][r] + (bias ? bias[col] : 0.f);
        if (MODE == 0){ Cf[(long long)row*ldc + col] = v; }
        if (MODE == 2){
          v = tanhf(v);
          if (Cf) Cf[(long long)row*ldc + col] = v;
          Ch[(long long)row*ldc + col] = f2bf(v);
        }
      }
    }
  }
}

// ---------------------------------------------------------------------------
// Fused persistent bi-LSTM (tagged packets, PIPELINED poll) + side work.
// Blocks 0..63: LSTM, 32/dir, 16 hidden units (64 gate cols), 512 thr.
// Consumer keeps 4 loads in flight (two register sets, vmcnt(4) alternation)
// so tag-detect costs ~1 LLC RTT instead of ~1.5.
// Blocks 64+: side tasks: tnp0(1), W_comboT(128), WjT(32), nullrow(63), WvT(4000).
// ---------------------------------------------------------------------------
__global__ __launch_bounds__(512, 1) void k_fused(
    const float* __restrict__ Xfw, const float* __restrict__ Xbw,
    const float* __restrict__ Wfw, const float* __restrict__ Wbw,
    unsigned int* __restrict__ hex32,
    unsigned short* __restrict__ Hcat_h,
    const int* __restrict__ tnull, const float* __restrict__ emb,
    const float* __restrict__ W1, const float* __restrict__ b1,
    const float* __restrict__ Wp, const float* __restrict__ bp,
    const float* __restrict__ Wv, const float* __restrict__ bv,
    unsigned short* __restrict__ WvT,
    float* __restrict__ lognull, float* __restrict__ nullsum,
    float* __restrict__ p0,
    const float* __restrict__ Wl, unsigned short* __restrict__ W_comboT,
    const float* __restrict__ Wj, unsigned short* __restrict__ WjT)
{
  __shared__ __align__(16) unsigned short W_s[64*512];   // 64 KB
  __shared__ __align__(16) float z_s[2][8][16][68];      // parity-dbuf
  const int bid = blockIdx.x;
  const int t = threadIdx.x;                 // 0..511

  if (bid >= 64){
    float* zflat = &z_s[0][0][0][0];
    int sid = bid - 64;
    if (sid == 0){
      float* en  = zflat;
      float* red = zflat + 256;
      if (t < E_) en[t] = emb[(long long)tnull[0]*E_ + t];
      __syncthreads();
      float s = b1[t];
      for (int e = 0; e < E_; e++) s += en[e]*W1[(long long)e*H_ + t];
      red[t] = tanhf(s)*Wp[t];
      __syncthreads();
      for (int w = 256; w > 0; w >>= 1){
        if (t < w) red[t] += red[t+w];
        __syncthreads();
      }
      if (t == 0) p0[0] = sigf(red[0] + bp[0])*0.3f;
      return;
    }
    sid -= 1;
    if (sid < 128){
      const int K8 = sid*8;
      float* WlS = zflat;            // [8][256]
      #pragma unroll
      for (int rep = 0; rep < 4; rep++){
        int id = rep*512 + t;
        int kl = id >> 8, e = id & 255;
        WlS[kl*256 + e] = Wl[(long long)(K8 + kl)*256 + e];
      }
      __syncthreads();
      float acc[8] = {};
      for (int e = 0; e < 256; e++){
        float w1v = W1[(long long)e*512 + t];
        #pragma unroll
        for (int j = 0; j < 8; j++) acc[j] += WlS[j*256 + e]*w1v;
      }
      #pragma unroll
      for (int j = 0; j < 8; j++)
        W_comboT[(long long)t*1024 + K8 + j] = f2bf(acc[j]);
      return;
    }
    sid -= 128;
    if (sid < 32){
      wtr_tile(Wj, WjT, SJ_, SJ_, 512, (sid & 3)*64, (sid >> 2)*64, zflat);
      return;
    }
    sid -= 32;
    if (sid < 63){
      float* en  = zflat;
      float* tns = zflat + 256;
      float* red = zflat + 768;
      if (t < E_) en[t] = emb[(long long)tnull[0]*E_ + t];
      __syncthreads();
      float s0 = b1[t];
      for (int e = 0; e < E_; e++) s0 += en[e]*W1[(long long)e*H_ + t];
      tns[t] = tanhf(s0);
      __syncthreads();
      int c = sid*512 + t;
      float p = 0.f;
      if (c < VS_){
        float s = bv[c];
        for (int k = 0; k < H_; k++) s += tns[k]*Wv[(long long)k*VS_ + c];
        lognull[c] = s;
        p = __expf(s);
      }
      red[t] = p;
      __syncthreads();
      for (int w = 256; w > 0; w >>= 1){
        if (t < w) red[t] += red[t+w];
        __syncthreads();
      }
      if (t == 0) atomicAdd(nullsum, red[0]);
      return;
    }
    sid -= 63;
    wtr_tile(Wv, WvT, VS_, VS_, H_, (sid % 500)*64, (sid / 500)*64, zflat);
    return;
  }

  // ---------------- LSTM path ----------------
  const int dir = bid >> 5;
  const int slice = bid & 31;
  const int u0 = slice * 16;
  const int lane = t & 63;
  const int w = t >> 6;                      // wave = K-eighth
  const int m = lane & 15, hi = lane >> 4;
  const float* X = dir ? Xbw : Xfw;
  const float* Wg = (dir ? Wbw : Wfw) + (long long)E_*2048;
  char* hexd = (char*)hex32 + dir*65536;

  for (int rep = 0; rep < 8; rep++){
    int id = rep*512 + t;
    int k = id >> 3, col8 = (id & 7)*8;
    int g = col8 >> 4, uu0 = col8 & 15;
    const float* src = Wg + (long long)k*2048 + g*512 + u0 + uu0;
    float4 w0 = *(const float4*)src;
    float4 w1 = *(const float4*)(src + 4);
    float wv8[8] = {w0.x,w0.y,w0.z,w0.w,w1.x,w1.y,w1.z,w1.w};
    #pragma unroll
    for (int j = 0; j < 8; j++){
      int c = col8 + j;
      int byte = (c << 10) + (k << 1);
      byte ^= ((c & 7) << 4);
      *(unsigned short*)((char*)W_s + byte) = f2bf(wv8[j]);
    }
  }
  __syncthreads();

  short8 bfr[4][2];
  #pragma unroll
  for (int nt = 0; nt < 4; nt++)
    #pragma unroll
    for (int ck = 0; ck < 2; ck++){
      int col = nt*16 + m;
      int kc = 2*w + ck;
      int byte = (col << 10) + kc*64 + hi*16;
      byte ^= ((col & 7) << 4);
      bfr[nt][ck] = *(const short8*)((const char*)W_s + byte);
    }

  const int eb = t >> 4, eu = t & 15;
  float creg = 0.f;

  for (int step = 0; step < J_; step++){
    const int par = step & 1;
    const int t_eff = dir ? (J_-1-step) : step;
    float xg0=0.f, xg1=0.f, xg2=0.f, xg3=0.f;
    if (t < 256){
      const float* xr = X + ((long long)eb*J_ + t_eff)*2048 + u0 + eu;
      xg0 = xr[0]; xg1 = xr[512]; xg2 = xr[1024]; xg3 = xr[1536];
      asm volatile("" : "+v"(xg0), "+v"(xg1), "+v"(xg2), "+v"(xg3));
    }
    // ---- pipelined poll of own A-frag packets ----
    const char* ap = hexd + par*32768 + m*2048 + w*256 + hi*32;
    u32x4 dA0, dA1, dA2, dA3, dB0, dB1, dB2, dB3;
    const unsigned expt = (unsigned)step;
    unsigned spin = 0;
    bool gotA = true;
    asm volatile("global_load_dwordx4 %0, %1, off sc0 sc1" : "=v"(dA0) : "v"(ap));
    asm volatile("global_load_dwordx4 %0, %1, off offset:16 sc0 sc1" : "=v"(dA1) : "v"(ap));
    asm volatile("global_load_dwordx4 %0, %1, off offset:128 sc0 sc1" : "=v"(dA2) : "v"(ap));
    asm volatile("global_load_dwordx4 %0, %1, off offset:144 sc0 sc1" : "=v"(dA3) : "v"(ap));
    for (;;){
      asm volatile("global_load_dwordx4 %0, %1, off sc0 sc1" : "=v"(dB0) : "v"(ap));
      asm volatile("global_load_dwordx4 %0, %1, off offset:16 sc0 sc1" : "=v"(dB1) : "v"(ap));
      asm volatile("global_load_dwordx4 %0, %1, off offset:128 sc0 sc1" : "=v"(dB2) : "v"(ap));
      asm volatile("global_load_dwordx4 %0, %1, off offset:144 sc0 sc1" : "=v"(dB3) : "v"(ap));
      asm volatile("s_waitcnt vmcnt(4)" ::: "memory");
      __builtin_amdgcn_sched_barrier(0);
      unsigned bad = (dA0[1]^expt)|(dA0[3]^expt)|(dA1[1]^expt)|(dA1[3]^expt)
                   | (dA2[1]^expt)|(dA2[3]^expt)|(dA3[1]^expt)|(dA3[3]^expt);
      if (__all(bad == 0u)){ gotA = true; break; }
      asm volatile("global_load_dwordx4 %0, %1, off sc0 sc1" : "=v"(dA0) : "v"(ap));
      asm volatile("global_load_dwordx4 %0, %1, off offset:16 sc0 sc1" : "=v"(dA1) : "v"(ap));
      asm volatile("global_load_dwordx4 %0, %1, off offset:128 sc0 sc1" : "=v"(dA2) : "v"(ap));
      asm volatile("global_load_dwordx4 %0, %1, off offset:144 sc0 sc1" : "=v"(dA3) : "v"(ap));
      asm volatile("s_waitcnt vmcnt(4)" ::: "memory");
      __builtin_amdgcn_sched_barrier(0);
      bad = (dB0[1]^expt)|(dB0[3]^expt)|(dB1[1]^expt)|(dB1[3]^expt)
          | (dB2[1]^expt)|(dB2[3]^expt)|(dB3[1]^expt)|(dB3[3]^expt);
      if (__all(bad == 0u)){ gotA = false; break; }
      if ((spin += 2) > 65536u){ gotA = true; break; }
    }
    asm volatile("s_waitcnt vmcnt(0)" ::: "memory");
    __builtin_amdgcn_sched_barrier(0);
    union { unsigned int u[4]; short8 s; } a0, a1;
    if (gotA){
      a0.u[0]=dA0[0]; a0.u[1]=dA0[2]; a0.u[2]=dA1[0]; a0.u[3]=dA1[2];
      a1.u[0]=dA2[0]; a1.u[1]=dA2[2]; a1.u[2]=dA3[0]; a1.u[3]=dA3[2];
    } else {
      a0.u[0]=dB0[0]; a0.u[1]=dB0[2]; a0.u[2]=dB1[0]; a0.u[3]=dB1[2];
      a1.u[0]=dB2[0]; a1.u[1]=dB2[2]; a1.u[2]=dB3[0]; a1.u[3]=dB3[2];
    }
    f32x4 acc[4] = {{0.f,0.f,0.f,0.f},{0.f,0.f,0.f,0.f},{0.f,0.f,0.f,0.f},{0.f,0.f,0.f,0.f}};
    #pragma unroll
    for (int nt = 0; nt < 4; nt++){
      acc[nt] = __builtin_amdgcn_mfma_f32_16x16x32_bf16(a0.s, bfr[nt][0], acc[nt], 0,0,0);
      acc[nt] = __builtin_amdgcn_mfma_f32_16x16x32_bf16(a1.s, bfr[nt][1], acc[nt], 0,0,0);
    }
    #pragma unroll
    for (int nt = 0; nt < 4; nt++)
      #pragma unroll
      for (int r = 0; r < 4; r++)
        z_s[par][w][hi*4 + r][nt*16 + m] = acc[nt][r];
    __syncthreads();
    if (t < 256){
      float z0 = xg0, z1 = xg1, z2 = xg2, z3 = xg3;
      #pragma unroll
      for (int ke = 0; ke < 8; ke++){
        z0 += z_s[par][ke][eb][eu];
        z1 += z_s[par][ke][eb][16 + eu];
        z2 += z_s[par][ke][eb][32 + eu];
        z3 += z_s[par][ke][eb][48 + eu];
      }
      creg = sigf(z2 + 1.f)*creg + sigf(z0)*tanhf(z1);
      float hh = sigf(z3)*tanhf(creg);
      unsigned int hb16 = (unsigned int)f2bf(hh);
      unsigned int nb = (unsigned int)__shfl_xor((int)hb16, 1);
      if (!(eu & 1)){
        unsigned long long pkt = (unsigned long long)((hb16 & 0xffffu) | (nb << 16))
                               | ((unsigned long long)(unsigned)(step+1) << 32);
        __hip_atomic_store((unsigned long long*)(hexd + (par^1)*32768 + eb*2048 + (u0 + eu)*4),
                           pkt, __ATOMIC_RELAXED, __HIP_MEMORY_SCOPE_AGENT);
      }
      Hcat_h[((long long)eb*J_ + t_eff)*1024 + dir*512 + u0 + eu] = (unsigned short)hb16;
    }
  }
}

// ---------------------------------------------------------------------------
// Mega tail: rowsum GEMM (3000) + jump-logit GEMM (24) + gathered numerators
// (144 blocks x 4 wave-tiles). All depend only on t1h (+ k_fused outputs).
// ---------------------------------------------------------------------------
__global__ __launch_bounds__(256, 2) void k_mega(
    const unsigned short* __restrict__ t1h,
    const unsigned short* __restrict__ WvT,
    const unsigned short* __restrict__ WjT,
    const float* __restrict__ bv, const float* __restrict__ bj,
    const int* __restrict__ sources,
    float* __restrict__ rowsum, float* __restrict__ jlog,
    float* __restrict__ out_em)
{
  __shared__ unsigned short As[128*32];
  __shared__ unsigned short Bs[128*32];
  const int t = threadIdx.x;
  const int lane = t & 63, w = t >> 6;
  int bid = blockIdx.x;
  if (bid >= 3024){
    // gathered-logit numerators: one 16x16 tile per wave
    int tile = (bid - 3024)*4 + w;            // 0..575
    int b = tile / 36, tl = tile % 36;
    int mt = tl / 6, nt = tl % 6;
    const int rr = lane & 15, kq = lane >> 4;
    int s = sources[b*96 + nt*16 + rr];
    float bg = bv[s];
    const unsigned short* arow = t1h + ((long long)(b*96 + mt*16 + rr))*512 + kq*8;
    const unsigned short* brow = WvT + (long long)s*512 + kq*8;
    f32x4 acc = {0.f,0.f,0.f,0.f};
    #pragma unroll
    for (int kc = 0; kc < 16; kc++){
      short8 af = *(const short8*)(arow + kc*32);
      short8 bf = *(const short8*)(brow + kc*32);
      acc = __builtin_amdgcn_mfma_f32_16x16x32_bf16(af, bf, acc, 0, 0, 0);
    }
    #pragma unroll
    for (int r = 0; r < 4; r++){
      int j = mt*16 + kq*4 + r;
      int i = nt*16 + rr;
      out_em[((long long)b*192 + j)*96 + i] = __expf(acc[r] + bg);
    }
    return;
  }
  const bool isjl = (bid >= 3000);
  int m0, n0;
  const unsigned short* Bh;
  if (isjl){
    int idx = bid - 3000;
    m0 = (idx % 12)*128; n0 = (idx / 12)*128;
    Bh = WjT;
  } else {
    int wg = (bid & 7)*375 + (bid >> 3);
    m0 = (wg % 12)*128; n0 = (wg / 12)*128;
    Bh = WvT;
  }
  f32x4 acc[4][4] = {};
  gemm128(t1h, Bh, H_, m0, n0, As, Bs, acc);
  const int wm = (w >> 1)*64, wn = (w & 1)*64;
  #pragma unroll
  for (int mi = 0; mi < 4; mi++){
    #pragma unroll
    for (int r = 0; r < 4; r++){
      int row = m0 + wm + mi*16 + ((lane >> 4) << 2) + r;
      if (isjl){
        #pragma unroll
        for (int ni = 0; ni < 4; ni++){
          int col = n0 + wn + ni*16 + (lane & 15);
          if (col < SJ_) jlog[(long long)row*SJ_ + col] = acc[mi][ni][r] + bj[col];
        }
      } else {
        float s = 0.f;
        #pragma unroll
        for (int ni = 0; ni < 4; ni++){
          int col = n0 + wn + ni*16 + (lane & 15);
          s += __expf(acc[mi][ni][r] + bv[col]);
        }
        s += __shfl_xor(s, 1);
        s += __shfl_xor(s, 2);
        s += __shfl_xor(s, 4);
        s += __shfl_xor(s, 8);
        if ((lane & 15) == 0) atomicAdd(&rowsum[row], s);
      }
    }
  }
}

// ---------------------------------------------------------------------------
// Final: transition + word-emission divide (blocks 0..1535) + null rows (16).
// ---------------------------------------------------------------------------
__global__ __launch_bounds__(128) void k_final(
    const float* __restrict__ jlog, const float* __restrict__ p0p,
    const float* __restrict__ rowsum,
    const float* __restrict__ lognull, const float* __restrict__ nullsum,
    const int* __restrict__ sources,
    float* __restrict__ out_em, float* __restrict__ T, float* __restrict__ TL)
{
  __shared__ float ex[128];
  __shared__ float red[128];
  int bx = blockIdx.x;
  int tid = threadIdx.x;
  if (bx >= NROW){
    int b = bx - NROW;
    if (tid < 96){
      int s = sources[b*96 + tid];
      float v = __expf(lognull[s]) / nullsum[0];
      for (int jj = 0; jj < 96; jj++)
        out_em[((long long)b*192 + 96 + jj)*96 + tid] = v;
    }
    return;
  }
  int b = bx / J_, j = bx % J_;
  // word-emission divide for row (b,j)
  float inv = 1.f / rowsum[bx];
  if (tid < 96)
    out_em[((long long)b*192 + j)*96 + tid] *= inv;
  // transition
  float e = 0.f;
  if (tid < 96) e = __expf(jlog[(long long)bx*SJ_ + (96 - j + tid)]);
  ex[tid] = e; red[tid] = e;
  __syncthreads();
  for (int w = 64; w > 0; w >>= 1){
    if (tid < w) red[tid] += red[tid+w];
    __syncthreads();
  }
  float p0 = p0p[0];
  float scale = (1.f - p0) / red[0];
  float lp0 = logf(p0);
  long long r0 = ((long long)b*192 + j)*192;
  long long r1 = ((long long)b*192 + j + 96)*192;
  for (int col = tid; col < 192; col += 128){
    float tv, lv;
    if (col < 96){ tv = ex[col]*scale; lv = logf(tv); }
    else { bool d = (col - 96) == j; tv = d ? p0 : 0.f; lv = d ? lp0 : 0.f; }
    T[r0 + col] = tv; T[r1 + col] = tv;
    TL[r0 + col] = lv; TL[r1 + col] = lv;
  }
}

extern "C" void kernel_launch(void* const* d_in, const int* in_sizes, int n_in,
                              void* d_out, int out_size, void* d_ws, size_t ws_size,
                              hipStream_t stream)
{
  const int* sources = (const int*)d_in[0];
  const int* targets = (const int*)d_in[1];
  const int* tnull   = (const int*)d_in[2];
  const float* emb   = (const float*)d_in[3];
  const float* Wfw   = (const float*)d_in[4];
  const float* bfw   = (const float*)d_in[5];
  const float* Wbw   = (const float*)d_in[6];
  const float* bbw   = (const float*)d_in[7];
  const float* Wl    = (const float*)d_in[8];
  const float* W1    = (const float*)d_in[9];
  const float* b1    = (const float*)d_in[10];
  const float* Wv    = (const float*)d_in[11];
  const float* bv    = (const float*)d_in[12];
  const float* Wj    = (const float*)d_in[13];
  const float* bj    = (const float*)d_in[14];
  const float* Wp    = (const float*)d_in[15];
  const float* bp    = (const float*)d_in[16];
  float* out = (float*)d_out;
  float* ws  = (float*)d_ws;

  long long off = 0;
  float* Xfw    = ws + off; off += (long long)NROW*2048;
  float* Xbw    = ws + off; off += (long long)NROW*2048;   // must follow Xfw (sC2)
  unsigned short* e_word_h = (unsigned short*)(ws + off); off += (long long)NROW*E_/2;
  unsigned short* WT       = (unsigned short*)(ws + off); off += 2LL*2048*256/2;
  unsigned short* Hcat_h   = (unsigned short*)(ws + off); off += (long long)NROW*1024/2;
  unsigned int* hex32 = (unsigned int*)(ws + off); off += 32768;
  unsigned short* t1h = (unsigned short*)(ws + off); off += (long long)NROW*H_/2;
  unsigned short* W_comboT = (unsigned short*)(ws + off); off += 512LL*1024/2;
  unsigned short* WjT      = (unsigned short*)(ws + off); off += 256LL*512/2;
  float* rowsum = ws + off; off += NROW;
  float* nullsum= ws + off; off += 1;
  float* p0     = ws + off; off += 1;
  float* wsb    = ws + off; off += 4096;
  float* lognull= ws + off; off += VS_;
  float* jlog   = ws + off; off += (long long)NROW*SJ_;
  unsigned short* WvT = (unsigned short*)(ws + off); off += (long long)VS_*H_/2;

  float* out_em = out;
  float* out_T  = out + (long long)B_*192*96;
  float* out_TL = out_T + (long long)B_*192*192;

  // 1) head: init + embed + W transposes + bias copy
  k_head<<<1943, 256, 0, stream>>>(targets, emb, e_word_h, Wfw, Wbw, WT,
                                   hex32, rowsum, bfw, bbw, wsb);

  // 2) input projections, both dirs in one launch (y selects dir)
  k_bgemm<0><<<dim3(192, 2), 256, 0, stream>>>(e_word_h, WT, E_, 2048, wsb,
                                               Xfw, nullptr, 2048,
                                               2048LL*256, 2048LL, (long long)NROW*2048);

  // 3) fused persistent tagged-packet bi-LSTM + side work
  k_fused<<<4288, 512, 0, stream>>>(Xfw, Xbw, Wfw, Wbw, hex32, Hcat_h,
                                    tnull, emb, W1, b1, Wp, bp, Wv, bv,
                                    WvT, lognull, nullsum, p0,
                                    Wl, W_comboT, Wj, WjT);

  // 4) t1h = bf16(tanh(Hcat @ (Wl@W1) + b1))
  k_bgemm<2><<<dim3(48, 1), 256, 0, stream>>>(Hcat_h, W_comboT, 2*H_, H_, b1,
                                              nullptr, t1h, H_, 0, 0, 0);

  // 5) mega tail: rowsum + jump logits + gathered numerators
  k_mega<<<3168, 256, 0, stream>>>(t1h, WvT, WjT, bv, bj, sources,
                                   rowsum, jlog, out_em);

  // 6) final: transition + emission divide + null rows
  k_final<<<NROW + B_, 128, 0, stream>>>(jlog, p0, rowsum, lognull, nullsum,
                                         sources, out_em, out_T, out_TL);
}

// Round 10
// 453.825 us; speedup vs baseline: 1.2457x; 1.2457x over previous
//
#include <hip/hip_runtime.h>
#include <math.h>

#define B_ 16
#define J_ 96
#define I_ 96
#define E_ 256
#define H_ 512
#define VS_ 32000
#define SJ_ 193
#define NROW (B_*J_)   // 1536

typedef __attribute__((ext_vector_type(8))) short short8;
typedef __attribute__((ext_vector_type(4))) float f32x4;
typedef __attribute__((ext_vector_type(4))) unsigned int u32x4;

__device__ __forceinline__ float sigf(float x){ return 1.f/(1.f+__expf(-x)); }

__device__ __forceinline__ unsigned short f2bf(float x){
  unsigned int u = __float_as_uint(x);
  unsigned int r = (u + 0x7FFFu + ((u>>16)&1u)) >> 16;
  return (unsigned short)r;
}

#define ASYNC16(gp, lp) __builtin_amdgcn_global_load_lds( \
    (const __attribute__((address_space(1))) unsigned int*)(gp), \
    (__attribute__((address_space(3))) unsigned int*)(lp), 16, 0, 0)

// 256-thr transpose+convert: src fp32 [K][ld] -> dst bf16 [N][K], zero-pad n>=nmax
__device__ __forceinline__ void wtr_tile256(const float* __restrict__ src,
                                            unsigned short* __restrict__ dst,
                                            int ldN, int nmax, int K, int n0, int k0,
                                            float* __restrict__ tile /*[64][65]*/)
{
  const int t = threadIdx.x;
  #pragma unroll
  for (int rep = 0; rep < 16; rep++){
    int idx = rep*256 + t;
    int kk = idx >> 6, nn = idx & 63;
    tile[kk*65 + nn] = (n0+nn < nmax) ? src[(long long)(k0+kk)*ldN + n0 + nn] : 0.f;
  }
  __syncthreads();
  #pragma unroll
  for (int rep = 0; rep < 16; rep++){
    int idx = rep*256 + t;
    int nn = idx >> 6, kk = idx & 63;
    dst[(long long)(n0+nn)*K + k0 + kk] = f2bf(tile[kk*65 + nn]);
  }
}

// 512-thr version (used in k_fused side tasks)
__device__ __forceinline__ void wtr_tile(const float* __restrict__ src,
                                         unsigned short* __restrict__ dst,
                                         int ldN, int nmax, int K, int n0, int k0,
                                         float* __restrict__ tile)
{
  const int t = threadIdx.x;
  #pragma unroll
  for (int rep = 0; rep < 8; rep++){
    int idx = rep*512 + t;
    int kk = idx >> 6, nn = idx & 63;
    tile[kk*65 + nn] = (n0+nn < nmax) ? src[(long long)(k0+kk)*ldN + n0 + nn] : 0.f;
  }
  __syncthreads();
  #pragma unroll
  for (int rep = 0; rep < 8; rep++){
    int idx = rep*512 + t;
    int nn = idx >> 6, kk = idx & 63;
    dst[(long long)(n0+nn)*K + k0 + kk] = f2bf(tile[kk*65 + nn]);
  }
}

// ---------------------------------------------------------------------------
// Head: init hex/rowsum, embed->bf16, Wfw/Wbw transpose, bias copy. One launch.
// grid = 1536(embed) + 256(wtr) + 128(hex0) + 7(rowsum0) + 16(biascopy) = 1943
// ---------------------------------------------------------------------------
__global__ __launch_bounds__(256) void k_head(
    const int* __restrict__ targets, const float* __restrict__ emb,
    unsigned short* __restrict__ e_word_h,
    const float* __restrict__ Wfw, const float* __restrict__ Wbw,
    unsigned short* __restrict__ WT,
    unsigned int* __restrict__ hex, float* __restrict__ rowsum,
    const float* __restrict__ bfw, const float* __restrict__ bbw,
    float* __restrict__ wsb)
{
  __shared__ float tile[64*65];
  int bid = blockIdx.x;
  const int t = threadIdx.x;
  if (bid < 1536){
    int tr = targets[bid];
    e_word_h[(long long)bid*E_ + t] = f2bf(emb[(long long)tr*E_ + t]);
    return;
  }
  bid -= 1536;
  if (bid < 256){
    int y = bid >> 7;
    const float* src = y ? Wbw : Wfw;
    unsigned short* dst = WT + (long long)y*2048*256;
    int sid = bid & 127;
    wtr_tile256(src, dst, 2048, 2048, 256, (sid & 31)*64, (sid >> 5)*64, tile);
    return;
  }
  bid -= 256;
  if (bid < 128){ hex[bid*256 + t] = 0u; return; }
  bid -= 128;
  if (bid < 7){
    int i = bid*256 + t;
    if (i < NROW + 1) rowsum[i] = 0.f;
    return;
  }
  bid -= 7;
  int i = bid*256 + t;                       // 16 blocks, 4096 floats
  wsb[i] = (i < 2048) ? bfw[i] : bbw[i - 2048];
}

// ---------------------------------------------------------------------------
// 128x128 bf16 MFMA K-loop (shared by k_bgemm and k_mega)
// ---------------------------------------------------------------------------
__device__ __forceinline__ void gemm128(const unsigned short* __restrict__ Ah,
                                        const unsigned short* __restrict__ Bh,
                                        int K, int m0, int n0,
                                        unsigned short* As, unsigned short* Bs,
                                        f32x4 (&acc)[4][4])
{
  const int t = threadIdx.x;
  const int lane = t & 63, w = t >> 6;
  const int wm = (w >> 1)*64, wn = (w & 1)*64;
  for (int k0 = 0; k0 < K; k0 += 32){
    #pragma unroll
    for (int p = 0; p < 2; p++){
      int rowA = p*64 + (t >> 2);
      int kc = (t & 3) ^ ((rowA >> 1) & 3);
      const unsigned short* ga = Ah + (long long)(m0 + rowA)*K + k0 + kc*8;
      const unsigned short* gb = Bh + (long long)(n0 + rowA)*K + k0 + kc*8;
      unsigned short* la = As + p*2048 + w*512;
      unsigned short* lb = Bs + p*2048 + w*512;
      ASYNC16(ga, la);
      ASYNC16(gb, lb);
    }
    __syncthreads();
    short8 af[4], bf[4];
    const int rr = lane & 15, kch = lane >> 4;
    #pragma unroll
    for (int mi = 0; mi < 4; mi++){
      int rowA = wm + mi*16 + rr;
      int slot = kch ^ ((rowA >> 1) & 3);
      af[mi] = *(const short8*)&As[rowA*32 + slot*8];
    }
    #pragma unroll
    for (int ni = 0; ni < 4; ni++){
      int rowB = wn + ni*16 + rr;
      int slot = kch ^ ((rowB >> 1) & 3);
      bf[ni] = *(const short8*)&Bs[rowB*32 + slot*8];
    }
    #pragma unroll
    for (int mi = 0; mi < 4; mi++)
      #pragma unroll
      for (int ni = 0; ni < 4; ni++)
        acc[mi][ni] = __builtin_amdgcn_mfma_f32_16x16x32_bf16(af[mi], bf[ni], acc[mi][ni], 0, 0, 0);
    __syncthreads();
  }
}

// Generic bf16 MFMA GEMM (BT layout). MODE 0: Cf=acc+bias; MODE 2: Ch=bf16(tanh(acc+bias)).
// gridDim.y==2 applies sB2/sBias2/sC2 to the second slice (dual-launch).
template<int MODE>
__global__ __launch_bounds__(256, 2) void k_bgemm(
    const unsigned short* __restrict__ Ah,
    const unsigned short* __restrict__ Bh,
    int K, int ncols,
    const float* __restrict__ bias,
    float* __restrict__ Cf,
    unsigned short* __restrict__ Ch,
    int ldc,
    long long sB2, long long sBias2, long long sC2)
{
  __shared__ unsigned short As[128*32];
  __shared__ unsigned short Bs[128*32];
  if (blockIdx.y){
    Bh += sB2;
    if (bias) bias += sBias2;
    if (Cf) Cf += sC2;
    if (Ch) Ch += sC2;
  }
  int nwg = gridDim.x;
  int braw = blockIdx.x;
  int wg = (braw & 7)*(nwg >> 3) + (braw >> 3);   // bijective: nwg % 8 == 0
  int mt = wg % 12, nt = wg / 12;
  const int m0 = mt*128, n0 = nt*128;
  f32x4 acc[4][4] = {};
  gemm128(Ah, Bh, K, m0, n0, As, Bs, acc);
  const int t = threadIdx.x;
  const int lane = t & 63, w = t >> 6;
  const int wm = (w >> 1)*64, wn = (w & 1)*64;
  #pragma unroll
  for (int mi = 0; mi < 4; mi++){
    #pragma unroll
    for (int r = 0; r < 4; r++){
      int row = m0 + wm + mi*16 + ((lane >> 4) << 2) + r;
      #pragma unroll
      for (int ni = 0; ni < 4; ni++){
        int col = n0 + wn + ni*16 + (lane & 15);
        if (col >= ncols) continue;
        float v = acc[mi][ni][r] + (bias ? bias[col] : 0.f);
        if (MODE == 0){ Cf[(long long)row*ldc + col] = v; }
        if (MODE == 2){
          v = tanhf(v);
          if (Cf) Cf[(long long)row*ldc + col] = v;
          Ch[(long long)row*ldc + col] = f2bf(v);
        }
      }
    }
  }
}

// ---------------------------------------------------------------------------
// Fused persistent bi-LSTM (tagged packets, r8-proven SIMPLE poll) + side work.
// Blocks 0..63: LSTM, 32/dir, 16 hidden units (64 gate cols), 512 thr.
//   Packet = u64 {bf16 h[2u], h[2u+1], tag}; producer: __hip_atomic_store u64
//   RELAXED/AGENT, tag=step+1, parity (step+1)&1. Consumer: serial poll
//   (issue 4 loads -> vmcnt(0) -> check) of its own A-frag packets for
//   tag==step. One barrier/step, z_s parity-double-buffered.
// Blocks 64+: side tasks: tnp0(1), W_comboT(128), WjT(32), nullrow(63), WvT(4000).
// ---------------------------------------------------------------------------
__global__ __launch_bounds__(512, 1) void k_fused(
    const float* __restrict__ Xfw, const float* __restrict__ Xbw,
    const float* __restrict__ Wfw, const float* __restrict__ Wbw,
    unsigned int* __restrict__ hex32,
    unsigned short* __restrict__ Hcat_h,
    const int* __restrict__ tnull, const float* __restrict__ emb,
    const float* __restrict__ W1, const float* __restrict__ b1,
    const float* __restrict__ Wp, const float* __restrict__ bp,
    const float* __restrict__ Wv, const float* __restrict__ bv,
    unsigned short* __restrict__ WvT,
    float* __restrict__ lognull, float* __restrict__ nullsum,
    float* __restrict__ p0,
    const float* __restrict__ Wl, unsigned short* __restrict__ W_comboT,
    const float* __restrict__ Wj, unsigned short* __restrict__ WjT)
{
  __shared__ __align__(16) unsigned short W_s[64*512];   // 64 KB
  __shared__ __align__(16) float z_s[2][8][16][68];      // parity-dbuf
  const int bid = blockIdx.x;
  const int t = threadIdx.x;                 // 0..511

  if (bid >= 64){
    float* zflat = &z_s[0][0][0][0];
    int sid = bid - 64;
    if (sid == 0){
      float* en  = zflat;
      float* red = zflat + 256;
      if (t < E_) en[t] = emb[(long long)tnull[0]*E_ + t];
      __syncthreads();
      float s = b1[t];
      for (int e = 0; e < E_; e++) s += en[e]*W1[(long long)e*H_ + t];
      red[t] = tanhf(s)*Wp[t];
      __syncthreads();
      for (int w = 256; w > 0; w >>= 1){
        if (t < w) red[t] += red[t+w];
        __syncthreads();
      }
      if (t == 0) p0[0] = sigf(red[0] + bp[0])*0.3f;
      return;
    }
    sid -= 1;
    if (sid < 128){
      const int K8 = sid*8;
      float* WlS = zflat;            // [8][256]
      #pragma unroll
      for (int rep = 0; rep < 4; rep++){
        int id = rep*512 + t;
        int kl = id >> 8, e = id & 255;
        WlS[kl*256 + e] = Wl[(long long)(K8 + kl)*256 + e];
      }
      __syncthreads();
      float acc[8] = {};
      for (int e = 0; e < 256; e++){
        float w1v = W1[(long long)e*512 + t];
        #pragma unroll
        for (int j = 0; j < 8; j++) acc[j] += WlS[j*256 + e]*w1v;
      }
      #pragma unroll
      for (int j = 0; j < 8; j++)
        W_comboT[(long long)t*1024 + K8 + j] = f2bf(acc[j]);
      return;
    }
    sid -= 128;
    if (sid < 32){
      wtr_tile(Wj, WjT, SJ_, SJ_, 512, (sid & 3)*64, (sid >> 2)*64, zflat);
      return;
    }
    sid -= 32;
    if (sid < 63){
      float* en  = zflat;
      float* tns = zflat + 256;
      float* red = zflat + 768;
      if (t < E_) en[t] = emb[(long long)tnull[0]*E_ + t];
      __syncthreads();
      float s0 = b1[t];
      for (int e = 0; e < E_; e++) s0 += en[e]*W1[(long long)e*H_ + t];
      tns[t] = tanhf(s0);
      __syncthreads();
      int c = sid*512 + t;
      float p = 0.f;
      if (c < VS_){
        float s = bv[c];
        for (int k = 0; k < H_; k++) s += tns[k]*Wv[(long long)k*VS_ + c];
        lognull[c] = s;
        p = __expf(s);
      }
      red[t] = p;
      __syncthreads();
      for (int w = 256; w > 0; w >>= 1){
        if (t < w) red[t] += red[t+w];
        __syncthreads();
      }
      if (t == 0) atomicAdd(nullsum, red[0]);
      return;
    }
    sid -= 63;
    wtr_tile(Wv, WvT, VS_, VS_, H_, (sid % 500)*64, (sid / 500)*64, zflat);
    return;
  }

  // ---------------- LSTM path ----------------
  const int dir = bid >> 5;
  const int slice = bid & 31;
  const int u0 = slice * 16;
  const int lane = t & 63;
  const int w = t >> 6;                      // wave = K-eighth
  const int m = lane & 15, hi = lane >> 4;
  const float* X = dir ? Xbw : Xfw;
  const float* Wg = (dir ? Wbw : Wfw) + (long long)E_*2048;
  char* hexd = (char*)hex32 + dir*65536;

  for (int rep = 0; rep < 8; rep++){
    int id = rep*512 + t;
    int k = id >> 3, col8 = (id & 7)*8;
    int g = col8 >> 4, uu0 = col8 & 15;
    const float* src = Wg + (long long)k*2048 + g*512 + u0 + uu0;
    float4 w0 = *(const float4*)src;
    float4 w1 = *(const float4*)(src + 4);
    float wv8[8] = {w0.x,w0.y,w0.z,w0.w,w1.x,w1.y,w1.z,w1.w};
    #pragma unroll
    for (int j = 0; j < 8; j++){
      int c = col8 + j;
      int byte = (c << 10) + (k << 1);
      byte ^= ((c & 7) << 4);
      *(unsigned short*)((char*)W_s + byte) = f2bf(wv8[j]);
    }
  }
  __syncthreads();

  short8 bfr[4][2];
  #pragma unroll
  for (int nt = 0; nt < 4; nt++)
    #pragma unroll
    for (int ck = 0; ck < 2; ck++){
      int col = nt*16 + m;
      int kc = 2*w + ck;
      int byte = (col << 10) + kc*64 + hi*16;
      byte ^= ((col & 7) << 4);
      bfr[nt][ck] = *(const short8*)((const char*)W_s + byte);
    }

  const int eb = t >> 4, eu = t & 15;
  float creg = 0.f;

  for (int step = 0; step < J_; step++){
    const int par = step & 1;
    const int t_eff = dir ? (J_-1-step) : step;
    float xg0=0.f, xg1=0.f, xg2=0.f, xg3=0.f;
    if (t < 256){
      const float* xr = X + ((long long)eb*J_ + t_eff)*2048 + u0 + eu;
      xg0 = xr[0]; xg1 = xr[512]; xg2 = xr[1024]; xg3 = xr[1536];
      asm volatile("" : "+v"(xg0), "+v"(xg1), "+v"(xg2), "+v"(xg3));
    }
    // ---- r8-proven simple poll of own A-frag packets ----
    const char* ap = hexd + par*32768 + m*2048 + w*256 + hi*32;
    u32x4 d0, d1, d2, d3;
    const unsigned expt = (unsigned)step;
    unsigned spin = 0;
    for (;;){
      asm volatile("global_load_dwordx4 %0, %1, off sc0 sc1" : "=v"(d0) : "v"(ap));
      asm volatile("global_load_dwordx4 %0, %1, off offset:16 sc0 sc1" : "=v"(d1) : "v"(ap));
      asm volatile("global_load_dwordx4 %0, %1, off offset:128 sc0 sc1" : "=v"(d2) : "v"(ap));
      asm volatile("global_load_dwordx4 %0, %1, off offset:144 sc0 sc1" : "=v"(d3) : "v"(ap));
      asm volatile("s_waitcnt vmcnt(0)" ::: "memory");
      unsigned bad = (d0[1]^expt)|(d0[3]^expt)|(d1[1]^expt)|(d1[3]^expt)
                   | (d2[1]^expt)|(d2[3]^expt)|(d3[1]^expt)|(d3[3]^expt);
      if (__all(bad == 0u)) break;
      if (++spin > 65536u) break;            // bounded-spin escape (fail clean)
      __builtin_amdgcn_s_sleep(1);
    }
    __builtin_amdgcn_sched_barrier(0);
    // strip tags -> A-frags
    union { unsigned int u[4]; short8 s; } a0, a1;
    a0.u[0]=d0[0]; a0.u[1]=d0[2]; a0.u[2]=d1[0]; a0.u[3]=d1[2];
    a1.u[0]=d2[0]; a1.u[1]=d2[2]; a1.u[2]=d3[0]; a1.u[3]=d3[2];
    f32x4 acc[4] = {{0.f,0.f,0.f,0.f},{0.f,0.f,0.f,0.f},{0.f,0.f,0.f,0.f},{0.f,0.f,0.f,0.f}};
    #pragma unroll
    for (int nt = 0; nt < 4; nt++){
      acc[nt] = __builtin_amdgcn_mfma_f32_16x16x32_bf16(a0.s, bfr[nt][0], acc[nt], 0,0,0);
      acc[nt] = __builtin_amdgcn_mfma_f32_16x16x32_bf16(a1.s, bfr[nt][1], acc[nt], 0,0,0);
    }
    #pragma unroll
    for (int nt = 0; nt < 4; nt++)
      #pragma unroll
      for (int r = 0; r < 4; r++)
        z_s[par][w][hi*4 + r][nt*16 + m] = acc[nt][r];
    __syncthreads();                  // single barrier per step
    if (t < 256){
      float z0 = xg0, z1 = xg1, z2 = xg2, z3 = xg3;
      #pragma unroll
      for (int ke = 0; ke < 8; ke++){
        z0 += z_s[par][ke][eb][eu];
        z1 += z_s[par][ke][eb][16 + eu];
        z2 += z_s[par][ke][eb][32 + eu];
        z3 += z_s[par][ke][eb][48 + eu];
      }
      creg = sigf(z2 + 1.f)*creg + sigf(z0)*tanhf(z1);
      float hh = sigf(z3)*tanhf(creg);
      unsigned int hb16 = (unsigned int)f2bf(hh);
      unsigned int nb = (unsigned int)__shfl_xor((int)hb16, 1);
      if (!(eu & 1)){
        unsigned long long pkt = (unsigned long long)((hb16 & 0xffffu) | (nb << 16))
                               | ((unsigned long long)(unsigned)(step+1) << 32);
        __hip_atomic_store((unsigned long long*)(hexd + (par^1)*32768 + eb*2048 + (u0 + eu)*4),
                           pkt, __ATOMIC_RELAXED, __HIP_MEMORY_SCOPE_AGENT);
      }
      Hcat_h[((long long)eb*J_ + t_eff)*1024 + dir*512 + u0 + eu] = (unsigned short)hb16;
    }
  }
}

// ---------------------------------------------------------------------------
// Mega tail: rowsum GEMM (3000) + jump-logit GEMM (24) + gathered numerators
// (144 blocks x 4 wave-tiles). All depend only on t1h (+ k_fused outputs).
// ---------------------------------------------------------------------------
__global__ __launch_bounds__(256, 2) void k_mega(
    const unsigned short* __restrict__ t1h,
    const unsigned short* __restrict__ WvT,
    const unsigned short* __restrict__ WjT,
    const float* __restrict__ bv, const float* __restrict__ bj,
    const int* __restrict__ sources,
    float* __restrict__ rowsum, float* __restrict__ jlog,
    float* __restrict__ out_em)
{
  __shared__ unsigned short As[128*32];
  __shared__ unsigned short Bs[128*32];
  const int t = threadIdx.x;
  const int lane = t & 63, w = t >> 6;
  int bid = blockIdx.x;
  if (bid >= 3024){
    // gathered-logit numerators: one 16x16 tile per wave
    int tile = (bid - 3024)*4 + w;            // 0..575
    int b = tile / 36, tl = tile % 36;
    int mt = tl / 6, nt = tl % 6;
    const int rr = lane & 15, kq = lane >> 4;
    int s = sources[b*96 + nt*16 + rr];
    float bg = bv[s];
    const unsigned short* arow = t1h + ((long long)(b*96 + mt*16 + rr))*512 + kq*8;
    const unsigned short* brow = WvT + (long long)s*512 + kq*8;
    f32x4 acc = {0.f,0.f,0.f,0.f};
    #pragma unroll
    for (int kc = 0; kc < 16; kc++){
      short8 af = *(const short8*)(arow + kc*32);
      short8 bf = *(const short8*)(brow + kc*32);
      acc = __builtin_amdgcn_mfma_f32_16x16x32_bf16(af, bf, acc, 0, 0, 0);
    }
    #pragma unroll
    for (int r = 0; r < 4; r++){
      int j = mt*16 + kq*4 + r;
      int i = nt*16 + rr;
      out_em[((long long)b*192 + j)*96 + i] = __expf(acc[r] + bg);
    }
    return;
  }
  const bool isjl = (bid >= 3000);
  int m0, n0;
  const unsigned short* Bh;
  if (isjl){
    int idx = bid - 3000;
    m0 = (idx % 12)*128; n0 = (idx / 12)*128;
    Bh = WjT;
  } else {
    int wg = (bid & 7)*375 + (bid >> 3);
    m0 = (wg % 12)*128; n0 = (wg / 12)*128;
    Bh = WvT;
  }
  f32x4 acc[4][4] = {};
  gemm128(t1h, Bh, H_, m0, n0, As, Bs, acc);
  const int wm = (w >> 1)*64, wn = (w & 1)*64;
  #pragma unroll
  for (int mi = 0; mi < 4; mi++){
    #pragma unroll
    for (int r = 0; r < 4; r++){
      int row = m0 + wm + mi*16 + ((lane >> 4) << 2) + r;
      if (isjl){
        #pragma unroll
        for (int ni = 0; ni < 4; ni++){
          int col = n0 + wn + ni*16 + (lane & 15);
          if (col < SJ_) jlog[(long long)row*SJ_ + col] = acc[mi][ni][r] + bj[col];
        }
      } else {
        float s = 0.f;
        #pragma unroll
        for (int ni = 0; ni < 4; ni++){
          int col = n0 + wn + ni*16 + (lane & 15);
          s += __expf(acc[mi][ni][r] + bv[col]);
        }
        s += __shfl_xor(s, 1);
        s += __shfl_xor(s, 2);
        s += __shfl_xor(s, 4);
        s += __shfl_xor(s, 8);
        if ((lane & 15) == 0) atomicAdd(&rowsum[row], s);
      }
    }
  }
}

// ---------------------------------------------------------------------------
// Final: transition + word-emission divide (blocks 0..1535) + null rows (16).
// ---------------------------------------------------------------------------
__global__ __launch_bounds__(128) void k_final(
    const float* __restrict__ jlog, const float* __restrict__ p0p,
    const float* __restrict__ rowsum,
    const float* __restrict__ lognull, const float* __restrict__ nullsum,
    const int* __restrict__ sources,
    float* __restrict__ out_em, float* __restrict__ T, float* __restrict__ TL)
{
  __shared__ float ex[128];
  __shared__ float red[128];
  int bx = blockIdx.x;
  int tid = threadIdx.x;
  if (bx >= NROW){
    int b = bx - NROW;
    if (tid < 96){
      int s = sources[b*96 + tid];
      float v = __expf(lognull[s]) / nullsum[0];
      for (int jj = 0; jj < 96; jj++)
        out_em[((long long)b*192 + 96 + jj)*96 + tid] = v;
    }
    return;
  }
  int b = bx / J_, j = bx % J_;
  // word-emission divide for row (b,j)
  float inv = 1.f / rowsum[bx];
  if (tid < 96)
    out_em[((long long)b*192 + j)*96 + tid] *= inv;
  // transition
  float e = 0.f;
  if (tid < 96) e = __expf(jlog[(long long)bx*SJ_ + (96 - j + tid)]);
  ex[tid] = e; red[tid] = e;
  __syncthreads();
  for (int w = 64; w > 0; w >>= 1){
    if (tid < w) red[tid] += red[tid+w];
    __syncthreads();
  }
  float p0 = p0p[0];
  float scale = (1.f - p0) / red[0];
  float lp0 = logf(p0);
  long long r0 = ((long long)b*192 + j)*192;
  long long r1 = ((long long)b*192 + j + 96)*192;
  for (int col = tid; col < 192; col += 128){
    float tv, lv;
    if (col < 96){ tv = ex[col]*scale; lv = logf(tv); }
    else { bool d = (col - 96) == j; tv = d ? p0 : 0.f; lv = d ? lp0 : 0.f; }
    T[r0 + col] = tv; T[r1 + col] = tv;
    TL[r0 + col] = lv; TL[r1 + col] = lv;
  }
}

extern "C" void kernel_launch(void* const* d_in, const int* in_sizes, int n_in,
                              void* d_out, int out_size, void* d_ws, size_t ws_size,
                              hipStream_t stream)
{
  const int* sources = (const int*)d_in[0];
  const int* targets = (const int*)d_in[1];
  const int* tnull   = (const int*)d_in[2];
  const float* emb   = (const float*)d_in[3];
  const float* Wfw   = (const float*)d_in[4];
  const float* bfw   = (const float*)d_in[5];
  const float* Wbw   = (const float*)d_in[6];
  const float* bbw   = (const float*)d_in[7];
  const float* Wl    = (const float*)d_in[8];
  const float* W1    = (const float*)d_in[9];
  const float* b1    = (const float*)d_in[10];
  const float* Wv    = (const float*)d_in[11];
  const float* bv    = (const float*)d_in[12];
  const float* Wj    = (const float*)d_in[13];
  const float* bj    = (const float*)d_in[14];
  const float* Wp    = (const float*)d_in[15];
  const float* bp    = (const float*)d_in[16];
  float* out = (float*)d_out;
  float* ws  = (float*)d_ws;

  long long off = 0;
  float* Xfw    = ws + off; off += (long long)NROW*2048;
  float* Xbw    = ws + off; off += (long long)NROW*2048;   // must follow Xfw (sC2)
  unsigned short* e_word_h = (unsigned short*)(ws + off); off += (long long)NROW*E_/2;
  unsigned short* WT       = (unsigned short*)(ws + off); off += 2LL*2048*256/2;
  unsigned short* Hcat_h   = (unsigned short*)(ws + off); off += (long long)NROW*1024/2;
  unsigned int* hex32 = (unsigned int*)(ws + off); off += 32768;
  unsigned short* t1h = (unsigned short*)(ws + off); off += (long long)NROW*H_/2;
  unsigned short* W_comboT = (unsigned short*)(ws + off); off += 512LL*1024/2;
  unsigned short* WjT      = (unsigned short*)(ws + off); off += 256LL*512/2;
  float* rowsum = ws + off; off += NROW;
  float* nullsum= ws + off; off += 1;
  float* p0     = ws + off; off += 1;
  float* wsb    = ws + off; off += 4096;
  float* lognull= ws + off; off += VS_;
  float* jlog   = ws + off; off += (long long)NROW*SJ_;
  unsigned short* WvT = (unsigned short*)(ws + off); off += (long long)VS_*H_/2;

  float* out_em = out;
  float* out_T  = out + (long long)B_*192*96;
  float* out_TL = out_T + (long long)B_*192*192;

  // 1) head: init + embed + W transposes + bias copy
  k_head<<<1943, 256, 0, stream>>>(targets, emb, e_word_h, Wfw, Wbw, WT,
                                   hex32, rowsum, bfw, bbw, wsb);

  // 2) input projections, both dirs in one launch (y selects dir)
  k_bgemm<0><<<dim3(192, 2), 256, 0, stream>>>(e_word_h, WT, E_, 2048, wsb,
                                               Xfw, nullptr, 2048,
                                               2048LL*256, 2048LL, (long long)NROW*2048);

  // 3) fused persistent tagged-packet bi-LSTM + side work
  k_fused<<<4288, 512, 0, stream>>>(Xfw, Xbw, Wfw, Wbw, hex32, Hcat_h,
                                    tnull, emb, W1, b1, Wp, bp, Wv, bv,
                                    WvT, lognull, nullsum, p0,
                                    Wl, W_comboT, Wj, WjT);

  // 4) t1h = bf16(tanh(Hcat @ (Wl@W1) + b1))
  k_bgemm<2><<<dim3(48, 1), 256, 0, stream>>>(Hcat_h, W_comboT, 2*H_, H_, b1,
                                              nullptr, t1h, H_, 0, 0, 0);

  // 5) mega tail: rowsum + jump logits + gathered numerators
  k_mega<<<3168, 256, 0, stream>>>(t1h, WvT, WjT, bv, bj, sources,
                                   rowsum, jlog, out_em);

  // 6) final: transition + emission divide + null rows
  k_final<<<NROW + B_, 128, 0, stream>>>(jlog, p0, rowsum, lognull, nullsum,
                                         sources, out_em, out_T, out_TL);
}

// Round 11
// 443.122 us; speedup vs baseline: 1.2757x; 1.0242x over previous
//
#include <hip/hip_runtime.h>
#include <math.h>

#define B_ 16
#define J_ 96
#define I_ 96
#define E_ 256
#define H_ 512
#define VS_ 32000
#define SJ_ 193
#define NROW (B_*J_)   // 1536

typedef __attribute__((ext_vector_type(8))) short short8;
typedef __attribute__((ext_vector_type(4))) float f32x4;
typedef __attribute__((ext_vector_type(4))) unsigned int u32x4;

__device__ __forceinline__ float sigf(float x){ return 1.f/(1.f+__expf(-x)); }

__device__ __forceinline__ unsigned short f2bf(float x){
  unsigned int u = __float_as_uint(x);
  unsigned int r = (u + 0x7FFFu + ((u>>16)&1u)) >> 16;
  return (unsigned short)r;
}
__device__ __forceinline__ float bf2f(unsigned short u){
  return __uint_as_float((unsigned int)u << 16);
}

#define ASYNC16(gp, lp) __builtin_amdgcn_global_load_lds( \
    (const __attribute__((address_space(1))) unsigned int*)(gp), \
    (__attribute__((address_space(3))) unsigned int*)(lp), 16, 0, 0)

// 256-thr transpose+convert: src fp32 [K][ld] -> dst bf16 [N][K], zero-pad n>=nmax
__device__ __forceinline__ void wtr_tile256(const float* __restrict__ src,
                                            unsigned short* __restrict__ dst,
                                            int ldN, int nmax, int K, int n0, int k0,
                                            float* __restrict__ tile /*[64][65]*/)
{
  const int t = threadIdx.x;
  #pragma unroll
  for (int rep = 0; rep < 16; rep++){
    int idx = rep*256 + t;
    int kk = idx >> 6, nn = idx & 63;
    tile[kk*65 + nn] = (n0+nn < nmax) ? src[(long long)(k0+kk)*ldN + n0 + nn] : 0.f;
  }
  __syncthreads();
  #pragma unroll
  for (int rep = 0; rep < 16; rep++){
    int idx = rep*256 + t;
    int nn = idx >> 6, kk = idx & 63;
    dst[(long long)(n0+nn)*K + k0 + kk] = f2bf(tile[kk*65 + nn]);
  }
}

// 512-thr version (used in k_fused side tasks)
__device__ __forceinline__ void wtr_tile(const float* __restrict__ src,
                                         unsigned short* __restrict__ dst,
                                         int ldN, int nmax, int K, int n0, int k0,
                                         float* __restrict__ tile)
{
  const int t = threadIdx.x;
  #pragma unroll
  for (int rep = 0; rep < 8; rep++){
    int idx = rep*512 + t;
    int kk = idx >> 6, nn = idx & 63;
    tile[kk*65 + nn] = (n0+nn < nmax) ? src[(long long)(k0+kk)*ldN + n0 + nn] : 0.f;
  }
  __syncthreads();
  #pragma unroll
  for (int rep = 0; rep < 8; rep++){
    int idx = rep*512 + t;
    int nn = idx >> 6, kk = idx & 63;
    dst[(long long)(n0+nn)*K + k0 + kk] = f2bf(tile[kk*65 + nn]);
  }
}

// ---------------------------------------------------------------------------
// Head: init hex/rowsum, embed->bf16, Wfw/Wbw transpose, bias copy. One launch.
// grid = 1536(embed) + 256(wtr) + 128(hex0) + 7(rowsum0) + 16(biascopy) = 1943
// ---------------------------------------------------------------------------
__global__ __launch_bounds__(256) void k_head(
    const int* __restrict__ targets, const float* __restrict__ emb,
    unsigned short* __restrict__ e_word_h,
    const float* __restrict__ Wfw, const float* __restrict__ Wbw,
    unsigned short* __restrict__ WT,
    unsigned int* __restrict__ hex, float* __restrict__ rowsum,
    const float* __restrict__ bfw, const float* __restrict__ bbw,
    float* __restrict__ wsb)
{
  __shared__ float tile[64*65];
  int bid = blockIdx.x;
  const int t = threadIdx.x;
  if (bid < 1536){
    int tr = targets[bid];
    e_word_h[(long long)bid*E_ + t] = f2bf(emb[(long long)tr*E_ + t]);
    return;
  }
  bid -= 1536;
  if (bid < 256){
    int y = bid >> 7;
    const float* src = y ? Wbw : Wfw;
    unsigned short* dst = WT + (long long)y*2048*256;
    int sid = bid & 127;
    wtr_tile256(src, dst, 2048, 2048, 256, (sid & 31)*64, (sid >> 5)*64, tile);
    return;
  }
  bid -= 256;
  if (bid < 128){ hex[bid*256 + t] = 0u; return; }
  bid -= 128;
  if (bid < 7){
    int i = bid*256 + t;
    if (i < NROW + 1) rowsum[i] = 0.f;
    return;
  }
  bid -= 7;
  int i = bid*256 + t;                       // 16 blocks, 4096 floats
  wsb[i] = (i < 2048) ? bfw[i] : bbw[i - 2048];
}

// ---------------------------------------------------------------------------
// 128x128 bf16 MFMA K-loop, BK=64 (shared by k_bgemm and k_mega).
// LDS layout: row-major 128 rows x 128B; slot s in row r holds global chunk
// s ^ (r & 7) (involution, 2-way-max bank profile like the proven BK=32).
// ---------------------------------------------------------------------------
__device__ __forceinline__ void gemm128(const unsigned short* __restrict__ Ah,
                                        const unsigned short* __restrict__ Bh,
                                        int K, int m0, int n0,
                                        unsigned short* As, unsigned short* Bs,
                                        f32x4 (&acc)[4][4])
{
  const int t = threadIdx.x;
  const int lane = t & 63, w = t >> 6;
  const int wm = (w >> 1)*64, wn = (w & 1)*64;
  for (int k0 = 0; k0 < K; k0 += 64){
    #pragma unroll
    for (int p = 0; p < 4; p++){
      int rowA = p*32 + (t >> 3);            // 8 threads/row
      int kc = (t & 7) ^ (rowA & 7);
      const unsigned short* ga = Ah + (long long)(m0 + rowA)*K + k0 + kc*8;
      const unsigned short* gb = Bh + (long long)(n0 + rowA)*K + k0 + kc*8;
      unsigned short* la = As + p*2048 + w*512;   // bytes: p*4096 + w*1024 (+lane*16)
      unsigned short* lb = Bs + p*2048 + w*512;
      ASYNC16(ga, la);
      ASYNC16(gb, lb);
    }
    __syncthreads();
    const int rr = lane & 15, kch = lane >> 4;
    #pragma unroll
    for (int kk = 0; kk < 2; kk++){
      short8 af[4], bf[4];
      #pragma unroll
      for (int mi = 0; mi < 4; mi++){
        int rowA = wm + mi*16 + rr;
        int slot = (kk*4 + kch) ^ (rowA & 7);
        af[mi] = *(const short8*)&As[rowA*64 + slot*8];
      }
      #pragma unroll
      for (int ni = 0; ni < 4; ni++){
        int rowB = wn + ni*16 + rr;
        int slot = (kk*4 + kch) ^ (rowB & 7);
        bf[ni] = *(const short8*)&Bs[rowB*64 + slot*8];
      }
      #pragma unroll
      for (int mi = 0; mi < 4; mi++)
        #pragma unroll
        for (int ni = 0; ni < 4; ni++)
          acc[mi][ni] = __builtin_amdgcn_mfma_f32_16x16x32_bf16(af[mi], bf[ni], acc[mi][ni], 0, 0, 0);
    }
    __syncthreads();
  }
}

// Generic bf16 MFMA GEMM (BT layout). MODE 0: Cf=acc+bias; MODE 1: Ch=bf16(acc+bias);
// MODE 2: Ch=bf16(tanh(acc+bias)), Cf optional.
// gridDim.y==2 applies sB2/sBias2/sC2 to the second slice (dual-launch).
template<int MODE>
__global__ __launch_bounds__(256, 2) void k_bgemm(
    const unsigned short* __restrict__ Ah,
    const unsigned short* __restrict__ Bh,
    int K, int ncols,
    const float* __restrict__ bias,
    float* __restrict__ Cf,
    unsigned short* __restrict__ Ch,
    int ldc,
    long long sB2, long long sBias2, long long sC2)
{
  __shared__ unsigned short As[128*64];
  __shared__ unsigned short Bs[128*64];
  if (blockIdx.y){
    Bh += sB2;
    if (bias) bias += sBias2;
    if (Cf) Cf += sC2;
    if (Ch) Ch += sC2;
  }
  int nwg = gridDim.x;
  int braw = blockIdx.x;
  int wg = (braw & 7)*(nwg >> 3) + (braw >> 3);   // bijective: nwg % 8 == 0
  int mt = wg % 12, nt = wg / 12;
  const int m0 = mt*128, n0 = nt*128;
  f32x4 acc[4][4] = {};
  gemm128(Ah, Bh, K, m0, n0, As, Bs, acc);
  const int t = threadIdx.x;
  const int lane = t & 63, w = t >> 6;
  const int wm = (w >> 1)*64, wn = (w & 1)*64;
  #pragma unroll
  for (int mi = 0; mi < 4; mi++){
    #pragma unroll
    for (int r = 0; r < 4; r++){
      int row = m0 + wm + mi*16 + ((lane >> 4) << 2) + r;
      #pragma unroll
      for (int ni = 0; ni < 4; ni++){
        int col = n0 + wn + ni*16 + (lane & 15);
        if (col >= ncols) continue;
        float v = acc[mi][ni][r] + (bias ? bias[col] : 0.f);
        if (MODE == 0){ Cf[(long long)row*ldc + col] = v; }
        if (MODE == 1){ Ch[(long long)row*ldc + col] = f2bf(v); }
        if (MODE == 2){
          v = tanhf(v);
          if (Cf) Cf[(long long)row*ldc + col] = v;
          Ch[(long long)row*ldc + col] = f2bf(v);
        }
      }
    }
  }
}

// ---------------------------------------------------------------------------
// Fused persistent bi-LSTM (tagged packets, r8-proven SIMPLE poll) + side work.
// Blocks 0..63: LSTM, 32/dir, 16 hidden units (64 gate cols), 512 thr.
//   Packet = u64 {bf16 h[2u], h[2u+1], tag}; producer: __hip_atomic_store u64
//   RELAXED/AGENT, tag=step+1, parity (step+1)&1. Consumer: serial poll
//   (issue 4 loads -> vmcnt(0) -> check) of its own A-frag packets for
//   tag==step. One barrier/step, z_s parity-double-buffered.
// X is bf16 [dir][1536][2048].
// Blocks 64+: side tasks: tnp0(1), W_comboT(128), WjT(32), nullrow(63), WvT(4000).
// ---------------------------------------------------------------------------
__global__ __launch_bounds__(512, 1) void k_fused(
    const unsigned short* __restrict__ Xh,
    const float* __restrict__ Wfw, const float* __restrict__ Wbw,
    unsigned int* __restrict__ hex32,
    unsigned short* __restrict__ Hcat_h,
    const int* __restrict__ tnull, const float* __restrict__ emb,
    const float* __restrict__ W1, const float* __restrict__ b1,
    const float* __restrict__ Wp, const float* __restrict__ bp,
    const float* __restrict__ Wv, const float* __restrict__ bv,
    unsigned short* __restrict__ WvT,
    float* __restrict__ lognull, float* __restrict__ nullsum,
    float* __restrict__ p0,
    const float* __restrict__ Wl, unsigned short* __restrict__ W_comboT,
    const float* __restrict__ Wj, unsigned short* __restrict__ WjT)
{
  __shared__ __align__(16) unsigned short W_s[64*512];   // 64 KB
  __shared__ __align__(16) float z_s[2][8][16][68];      // parity-dbuf
  const int bid = blockIdx.x;
  const int t = threadIdx.x;                 // 0..511

  if (bid >= 64){
    float* zflat = &z_s[0][0][0][0];
    int sid = bid - 64;
    if (sid == 0){
      float* en  = zflat;
      float* red = zflat + 256;
      if (t < E_) en[t] = emb[(long long)tnull[0]*E_ + t];
      __syncthreads();
      float s = b1[t];
      for (int e = 0; e < E_; e++) s += en[e]*W1[(long long)e*H_ + t];
      red[t] = tanhf(s)*Wp[t];
      __syncthreads();
      for (int w = 256; w > 0; w >>= 1){
        if (t < w) red[t] += red[t+w];
        __syncthreads();
      }
      if (t == 0) p0[0] = sigf(red[0] + bp[0])*0.3f;
      return;
    }
    sid -= 1;
    if (sid < 128){
      const int K8 = sid*8;
      float* WlS = zflat;            // [8][256]
      #pragma unroll
      for (int rep = 0; rep < 4; rep++){
        int id = rep*512 + t;
        int kl = id >> 8, e = id & 255;
        WlS[kl*256 + e] = Wl[(long long)(K8 + kl)*256 + e];
      }
      __syncthreads();
      float acc[8] = {};
      for (int e = 0; e < 256; e++){
        float w1v = W1[(long long)e*512 + t];
        #pragma unroll
        for (int j = 0; j < 8; j++) acc[j] += WlS[j*256 + e]*w1v;
      }
      #pragma unroll
      for (int j = 0; j < 8; j++)
        W_comboT[(long long)t*1024 + K8 + j] = f2bf(acc[j]);
      return;
    }
    sid -= 128;
    if (sid < 32){
      wtr_tile(Wj, WjT, SJ_, SJ_, 512, (sid & 3)*64, (sid >> 2)*64, zflat);
      return;
    }
    sid -= 32;
    if (sid < 63){
      float* en  = zflat;
      float* tns = zflat + 256;
      float* red = zflat + 768;
      if (t < E_) en[t] = emb[(long long)tnull[0]*E_ + t];
      __syncthreads();
      float s0 = b1[t];
      for (int e = 0; e < E_; e++) s0 += en[e]*W1[(long long)e*H_ + t];
      tns[t] = tanhf(s0);
      __syncthreads();
      int c = sid*512 + t;
      float p = 0.f;
      if (c < VS_){
        float s = bv[c];
        for (int k = 0; k < H_; k++) s += tns[k]*Wv[(long long)k*VS_ + c];
        lognull[c] = s;
        p = __expf(s);
      }
      red[t] = p;
      __syncthreads();
      for (int w = 256; w > 0; w >>= 1){
        if (t < w) red[t] += red[t+w];
        __syncthreads();
      }
      if (t == 0) atomicAdd(nullsum, red[0]);
      return;
    }
    sid -= 63;
    wtr_tile(Wv, WvT, VS_, VS_, H_, (sid % 500)*64, (sid / 500)*64, zflat);
    return;
  }

  // ---------------- LSTM path ----------------
  const int dir = bid >> 5;
  const int slice = bid & 31;
  const int u0 = slice * 16;
  const int lane = t & 63;
  const int w = t >> 6;                      // wave = K-eighth
  const int m = lane & 15, hi = lane >> 4;
  const unsigned short* X = Xh + (long long)dir*NROW*2048;
  const float* Wg = (dir ? Wbw : Wfw) + (long long)E_*2048;
  char* hexd = (char*)hex32 + dir*65536;

  for (int rep = 0; rep < 8; rep++){
    int id = rep*512 + t;
    int k = id >> 3, col8 = (id & 7)*8;
    int g = col8 >> 4, uu0 = col8 & 15;
    const float* src = Wg + (long long)k*2048 + g*512 + u0 + uu0;
    float4 w0 = *(const float4*)src;
    float4 w1 = *(const float4*)(src + 4);
    float wv8[8] = {w0.x,w0.y,w0.z,w0.w,w1.x,w1.y,w1.z,w1.w};
    #pragma unroll
    for (int j = 0; j < 8; j++){
      int c = col8 + j;
      int byte = (c << 10) + (k << 1);
      byte ^= ((c & 7) << 4);
      *(unsigned short*)((char*)W_s + byte) = f2bf(wv8[j]);
    }
  }
  __syncthreads();

  short8 bfr[4][2];
  #pragma unroll
  for (int nt = 0; nt < 4; nt++)
    #pragma unroll
    for (int ck = 0; ck < 2; ck++){
      int col = nt*16 + m;
      int kc = 2*w + ck;
      int byte = (col << 10) + kc*64 + hi*16;
      byte ^= ((col & 7) << 4);
      bfr[nt][ck] = *(const short8*)((const char*)W_s + byte);
    }

  const int eb = t >> 4, eu = t & 15;
  float creg = 0.f;

  for (int step = 0; step < J_; step++){
    const int par = step & 1;
    const int t_eff = dir ? (J_-1-step) : step;
    float xg0=0.f, xg1=0.f, xg2=0.f, xg3=0.f;
    if (t < 256){
      const unsigned short* xr = X + ((long long)eb*J_ + t_eff)*2048 + u0 + eu;
      xg0 = bf2f(xr[0]); xg1 = bf2f(xr[512]); xg2 = bf2f(xr[1024]); xg3 = bf2f(xr[1536]);
      asm volatile("" : "+v"(xg0), "+v"(xg1), "+v"(xg2), "+v"(xg3));
    }
    // ---- r8-proven simple poll of own A-frag packets ----
    const char* ap = hexd + par*32768 + m*2048 + w*256 + hi*32;
    u32x4 d0, d1, d2, d3;
    const unsigned expt = (unsigned)step;
    unsigned spin = 0;
    for (;;){
      asm volatile("global_load_dwordx4 %0, %1, off sc0 sc1" : "=v"(d0) : "v"(ap));
      asm volatile("global_load_dwordx4 %0, %1, off offset:16 sc0 sc1" : "=v"(d1) : "v"(ap));
      asm volatile("global_load_dwordx4 %0, %1, off offset:128 sc0 sc1" : "=v"(d2) : "v"(ap));
      asm volatile("global_load_dwordx4 %0, %1, off offset:144 sc0 sc1" : "=v"(d3) : "v"(ap));
      asm volatile("s_waitcnt vmcnt(0)" ::: "memory");
      unsigned bad = (d0[1]^expt)|(d0[3]^expt)|(d1[1]^expt)|(d1[3]^expt)
                   | (d2[1]^expt)|(d2[3]^expt)|(d3[1]^expt)|(d3[3]^expt);
      if (__all(bad == 0u)) break;
      if (++spin > 65536u) break;            // bounded-spin escape (fail clean)
      __builtin_amdgcn_s_sleep(1);
    }
    __builtin_amdgcn_sched_barrier(0);
    // strip tags -> A-frags
    union { unsigned int u[4]; short8 s; } a0, a1;
    a0.u[0]=d0[0]; a0.u[1]=d0[2]; a0.u[2]=d1[0]; a0.u[3]=d1[2];
    a1.u[0]=d2[0]; a1.u[1]=d2[2]; a1.u[2]=d3[0]; a1.u[3]=d3[2];
    f32x4 acc[4] = {{0.f,0.f,0.f,0.f},{0.f,0.f,0.f,0.f},{0.f,0.f,0.f,0.f},{0.f,0.f,0.f,0.f}};
    #pragma unroll
    for (int nt = 0; nt < 4; nt++){
      acc[nt] = __builtin_amdgcn_mfma_f32_16x16x32_bf16(a0.s, bfr[nt][0], acc[nt], 0,0,0);
      acc[nt] = __builtin_amdgcn_mfma_f32_16x16x32_bf16(a1.s, bfr[nt][1], acc[nt], 0,0,0);
    }
    #pragma unroll
    for (int nt = 0; nt < 4; nt++)
      #pragma unroll
      for (int r = 0; r < 4; r++)
        z_s[par][w][hi*4 + r][nt*16 + m] = acc[nt][r];
    __syncthreads();                  // single barrier per step
    if (t < 256){
      float z0 = xg0, z1 = xg1, z2 = xg2, z3 = xg3;
      #pragma unroll
      for (int ke = 0; ke < 8; ke++){
        z0 += z_s[par][ke][eb][eu];
        z1 += z_s[par][ke][eb][16 + eu];
        z2 += z_s[par][ke][eb][32 + eu];
        z3 += z_s[par][ke][eb][48 + eu];
      }
      creg = sigf(z2 + 1.f)*creg + sigf(z0)*tanhf(z1);
      float hh = sigf(z3)*tanhf(creg);
      unsigned int hb16 = (unsigned int)f2bf(hh);
      unsigned int nb = (unsigned int)__shfl_xor((int)hb16, 1);
      if (!(eu & 1)){
        unsigned long long pkt = (unsigned long long)((hb16 & 0xffffu) | (nb << 16))
                               | ((unsigned long long)(unsigned)(step+1) << 32);
        __hip_atomic_store((unsigned long long*)(hexd + (par^1)*32768 + eb*2048 + (u0 + eu)*4),
                           pkt, __ATOMIC_RELAXED, __HIP_MEMORY_SCOPE_AGENT);
      }
      Hcat_h[((long long)eb*J_ + t_eff)*1024 + dir*512 + u0 + eu] = (unsigned short)hb16;
    }
  }
}

// ---------------------------------------------------------------------------
// Mega tail: rowsum GEMM (3000) + jump-logit GEMM (24) + gathered numerators
// (144 blocks x 4 wave-tiles). All depend only on t1h (+ k_fused outputs).
// ---------------------------------------------------------------------------
__global__ __launch_bounds__(256, 2) void k_mega(
    const unsigned short* __restrict__ t1h,
    const unsigned short* __restrict__ WvT,
    const unsigned short* __restrict__ WjT,
    const float* __restrict__ bv, const float* __restrict__ bj,
    const int* __restrict__ sources,
    float* __restrict__ rowsum, float* __restrict__ jlog,
    float* __restrict__ out_em)
{
  __shared__ unsigned short As[128*64];
  __shared__ unsigned short Bs[128*64];
  const int t = threadIdx.x;
  const int lane = t & 63, w = t >> 6;
  int bid = blockIdx.x;
  if (bid >= 3024){
    // gathered-logit numerators: one 16x16 tile per wave
    int tile = (bid - 3024)*4 + w;            // 0..575
    int b = tile / 36, tl = tile % 36;
    int mt = tl / 6, nt = tl % 6;
    const int rr = lane & 15, kq = lane >> 4;
    int s = sources[b*96 + nt*16 + rr];
    float bg = bv[s];
    const unsigned short* arow = t1h + ((long long)(b*96 + mt*16 + rr))*512 + kq*8;
    const unsigned short* brow = WvT + (long long)s*512 + kq*8;
    f32x4 acc = {0.f,0.f,0.f,0.f};
    #pragma unroll
    for (int kc = 0; kc < 16; kc++){
      short8 af = *(const short8*)(arow + kc*32);
      short8 bf = *(const short8*)(brow + kc*32);
      acc = __builtin_amdgcn_mfma_f32_16x16x32_bf16(af, bf, acc, 0, 0, 0);
    }
    #pragma unroll
    for (int r = 0; r < 4; r++){
      int j = mt*16 + kq*4 + r;
      int i = nt*16 + rr;
      out_em[((long long)b*192 + j)*96 + i] = __expf(acc[r] + bg);
    }
    return;
  }
  const bool isjl = (bid >= 3000);
  int m0, n0;
  const unsigned short* Bh;
  if (isjl){
    int idx = bid - 3000;
    m0 = (idx % 12)*128; n0 = (idx / 12)*128;
    Bh = WjT;
  } else {
    int wg = (bid & 7)*375 + (bid >> 3);
    m0 = (wg % 12)*128; n0 = (wg / 12)*128;
    Bh = WvT;
  }
  f32x4 acc[4][4] = {};
  gemm128(t1h, Bh, H_, m0, n0, As, Bs, acc);
  const int wm = (w >> 1)*64, wn = (w & 1)*64;
  #pragma unroll
  for (int mi = 0; mi < 4; mi++){
    #pragma unroll
    for (int r = 0; r < 4; r++){
      int row = m0 + wm + mi*16 + ((lane >> 4) << 2) + r;
      if (isjl){
        #pragma unroll
        for (int ni = 0; ni < 4; ni++){
          int col = n0 + wn + ni*16 + (lane & 15);
          if (col < SJ_) jlog[(long long)row*SJ_ + col] = acc[mi][ni][r] + bj[col];
        }
      } else {
        float s = 0.f;
        #pragma unroll
        for (int ni = 0; ni < 4; ni++){
          int col = n0 + wn + ni*16 + (lane & 15);
          s += __expf(acc[mi][ni][r] + bv[col]);
        }
        s += __shfl_xor(s, 1);
        s += __shfl_xor(s, 2);
        s += __shfl_xor(s, 4);
        s += __shfl_xor(s, 8);
        if ((lane & 15) == 0) atomicAdd(&rowsum[row], s);
      }
    }
  }
}

// ---------------------------------------------------------------------------
// Final: transition + word-emission divide (blocks 0..1535) + null rows (16).
// ---------------------------------------------------------------------------
__global__ __launch_bounds__(128) void k_final(
    const float* __restrict__ jlog, const float* __restrict__ p0p,
    const float* __restrict__ rowsum,
    const float* __restrict__ lognull, const float* __restrict__ nullsum,
    const int* __restrict__ sources,
    float* __restrict__ out_em, float* __restrict__ T, float* __restrict__ TL)
{
  __shared__ float ex[128];
  __shared__ float red[128];
  int bx = blockIdx.x;
  int tid = threadIdx.x;
  if (bx >= NROW){
    int b = bx - NROW;
    if (tid < 96){
      int s = sources[b*96 + tid];
      float v = __expf(lognull[s]) / nullsum[0];
      for (int jj = 0; jj < 96; jj++)
        out_em[((long long)b*192 + 96 + jj)*96 + tid] = v;
    }
    return;
  }
  int b = bx / J_, j = bx % J_;
  // word-emission divide for row (b,j)
  float inv = 1.f / rowsum[bx];
  if (tid < 96)
    out_em[((long long)b*192 + j)*96 + tid] *= inv;
  // transition
  float e = 0.f;
  if (tid < 96) e = __expf(jlog[(long long)bx*SJ_ + (96 - j + tid)]);
  ex[tid] = e; red[tid] = e;
  __syncthreads();
  for (int w = 64; w > 0; w >>= 1){
    if (tid < w) red[tid] += red[tid+w];
    __syncthreads();
  }
  float p0 = p0p[0];
  float scale = (1.f - p0) / red[0];
  float lp0 = logf(p0);
  long long r0 = ((long long)b*192 + j)*192;
  long long r1 = ((long long)b*192 + j + 96)*192;
  for (int col = tid; col < 192; col += 128){
    float tv, lv;
    if (col < 96){ tv = ex[col]*scale; lv = logf(tv); }
    else { bool d = (col - 96) == j; tv = d ? p0 : 0.f; lv = d ? lp0 : 0.f; }
    T[r0 + col] = tv; T[r1 + col] = tv;
    TL[r0 + col] = lv; TL[r1 + col] = lv;
  }
}

extern "C" void kernel_launch(void* const* d_in, const int* in_sizes, int n_in,
                              void* d_out, int out_size, void* d_ws, size_t ws_size,
                              hipStream_t stream)
{
  const int* sources = (const int*)d_in[0];
  const int* targets = (const int*)d_in[1];
  const int* tnull   = (const int*)d_in[2];
  const float* emb   = (const float*)d_in[3];
  const float* Wfw   = (const float*)d_in[4];
  const float* bfw   = (const float*)d_in[5];
  const float* Wbw   = (const float*)d_in[6];
  const float* bbw   = (const float*)d_in[7];
  const float* Wl    = (const float*)d_in[8];
  const float* W1    = (const float*)d_in[9];
  const float* b1    = (const float*)d_in[10];
  const float* Wv    = (const float*)d_in[11];
  const float* bv    = (const float*)d_in[12];
  const float* Wj    = (const float*)d_in[13];
  const float* bj    = (const float*)d_in[14];
  const float* Wp    = (const float*)d_in[15];
  const float* bp    = (const float*)d_in[16];
  float* out = (float*)d_out;
  float* ws  = (float*)d_ws;

  long long off = 0;
  unsigned short* Xh = (unsigned short*)(ws + off); off += 2LL*NROW*2048/2;  // bf16 [2dir][1536][2048]
  unsigned short* e_word_h = (unsigned short*)(ws + off); off += (long long)NROW*E_/2;
  unsigned short* WT       = (unsigned short*)(ws + off); off += 2LL*2048*256/2;
  unsigned short* Hcat_h   = (unsigned short*)(ws + off); off += (long long)NROW*1024/2;
  unsigned int* hex32 = (unsigned int*)(ws + off); off += 32768;
  unsigned short* t1h = (unsigned short*)(ws + off); off += (long long)NROW*H_/2;
  unsigned short* W_comboT = (unsigned short*)(ws + off); off += 512LL*1024/2;
  unsigned short* WjT      = (unsigned short*)(ws + off); off += 256LL*512/2;
  float* rowsum = ws + off; off += NROW;
  float* nullsum= ws + off; off += 1;
  float* p0     = ws + off; off += 1;
  float* wsb    = ws + off; off += 4096;
  float* lognull= ws + off; off += VS_;
  float* jlog   = ws + off; off += (long long)NROW*SJ_;
  unsigned short* WvT = (unsigned short*)(ws + off); off += (long long)VS_*H_/2;

  float* out_em = out;
  float* out_T  = out + (long long)B_*192*96;
  float* out_TL = out_T + (long long)B_*192*192;

  // 1) head: init + embed + W transposes + bias copy
  k_head<<<1943, 256, 0, stream>>>(targets, emb, e_word_h, Wfw, Wbw, WT,
                                   hex32, rowsum, bfw, bbw, wsb);

  // 2) input projections, both dirs in one launch (y selects dir), bf16 out
  k_bgemm<1><<<dim3(192, 2), 256, 0, stream>>>(e_word_h, WT, E_, 2048, wsb,
                                               nullptr, Xh, 2048,
                                               2048LL*256, 2048LL, (long long)NROW*2048);

  // 3) fused persistent tagged-packet bi-LSTM + side work
  k_fused<<<4288, 512, 0, stream>>>(Xh, Wfw, Wbw, hex32, Hcat_h,
                                    tnull, emb, W1, b1, Wp, bp, Wv, bv,
                                    WvT, lognull, nullsum, p0,
                                    Wl, W_comboT, Wj, WjT);

  // 4) t1h = bf16(tanh(Hcat @ (Wl@W1) + b1))
  k_bgemm<2><<<dim3(48, 1), 256, 0, stream>>>(Hcat_h, W_comboT, 2*H_, H_, b1,
                                              nullptr, t1h, H_, 0, 0, 0);

  // 5) mega tail: rowsum + jump logits + gathered numerators
  k_mega<<<3168, 256, 0, stream>>>(t1h, WvT, WjT, bv, bj, sources,
                                   rowsum, jlog, out_em);

  // 6) final: transition + emission divide + null rows
  k_final<<<NROW + B_, 128, 0, stream>>>(jlog, p0, rowsum, lognull, nullsum,
                                         sources, out_em, out_T, out_TL);
}

// Round 12
// 396.284 us; speedup vs baseline: 1.4265x; 1.1182x over previous
//
#include <hip/hip_runtime.h>
#include <math.h>

#define B_ 16
#define J_ 96
#define I_ 96
#define E_ 256
#define H_ 512
#define VS_ 32000
#define SJ_ 193
#define NROW (B_*J_)   // 1536

typedef __attribute__((ext_vector_type(8))) short short8;
typedef __attribute__((ext_vector_type(4))) float f32x4;
typedef __attribute__((ext_vector_type(4))) unsigned int u32x4;

__device__ __forceinline__ float rcpfast(float x){
  float r;
  asm volatile("v_rcp_f32 %0, %1" : "=v"(r) : "v"(x));
  return r;
}
__device__ __forceinline__ float sigfast(float x){
  return rcpfast(1.f + __expf(-x));
}
__device__ __forceinline__ float tanhfast(float x){
  float e = __expf(2.f*x);
  return 1.f - 2.f*rcpfast(e + 1.f);     // e=inf -> 1, e=0 -> -1
}

__device__ __forceinline__ unsigned short f2bf(float x){
  unsigned int u = __float_as_uint(x);
  unsigned int r = (u + 0x7FFFu + ((u>>16)&1u)) >> 16;
  return (unsigned short)r;
}

#define ASYNC16(gp, lp) __builtin_amdgcn_global_load_lds( \
    (const __attribute__((address_space(1))) unsigned int*)(gp), \
    (__attribute__((address_space(3))) unsigned int*)(lp), 16, 0, 0)

// 256-thr transpose+convert: src fp32 [K][ld] -> dst bf16 [N][K], zero-pad n>=nmax
__device__ __forceinline__ void wtr_tile256(const float* __restrict__ src,
                                            unsigned short* __restrict__ dst,
                                            int ldN, int nmax, int K, int n0, int k0,
                                            float* __restrict__ tile /*[64][65]*/)
{
  const int t = threadIdx.x;
  #pragma unroll
  for (int rep = 0; rep < 16; rep++){
    int idx = rep*256 + t;
    int kk = idx >> 6, nn = idx & 63;
    tile[kk*65 + nn] = (n0+nn < nmax) ? src[(long long)(k0+kk)*ldN + n0 + nn] : 0.f;
  }
  __syncthreads();
  #pragma unroll
  for (int rep = 0; rep < 16; rep++){
    int idx = rep*256 + t;
    int nn = idx >> 6, kk = idx & 63;
    dst[(long long)(n0+nn)*K + k0 + kk] = f2bf(tile[kk*65 + nn]);
  }
}

// 512-thr version (used in k_fused side tasks)
__device__ __forceinline__ void wtr_tile(const float* __restrict__ src,
                                         unsigned short* __restrict__ dst,
                                         int ldN, int nmax, int K, int n0, int k0,
                                         float* __restrict__ tile)
{
  const int t = threadIdx.x;
  #pragma unroll
  for (int rep = 0; rep < 8; rep++){
    int idx = rep*512 + t;
    int kk = idx >> 6, nn = idx & 63;
    tile[kk*65 + nn] = (n0+nn < nmax) ? src[(long long)(k0+kk)*ldN + n0 + nn] : 0.f;
  }
  __syncthreads();
  #pragma unroll
  for (int rep = 0; rep < 8; rep++){
    int idx = rep*512 + t;
    int nn = idx >> 6, kk = idx & 63;
    dst[(long long)(n0+nn)*K + k0 + kk] = f2bf(tile[kk*65 + nn]);
  }
}

// ---------------------------------------------------------------------------
// Head: init hex/rowsum, embed->bf16, Wfw/Wbw transpose, bias copy. One launch.
// ---------------------------------------------------------------------------
__global__ __launch_bounds__(256) void k_head(
    const int* __restrict__ targets, const float* __restrict__ emb,
    unsigned short* __restrict__ e_word_h,
    const float* __restrict__ Wfw, const float* __restrict__ Wbw,
    unsigned short* __restrict__ WT,
    unsigned int* __restrict__ hex, float* __restrict__ rowsum,
    const float* __restrict__ bfw, const float* __restrict__ bbw,
    float* __restrict__ wsb)
{
  __shared__ float tile[64*65];
  int bid = blockIdx.x;
  const int t = threadIdx.x;
  if (bid < 1536){
    int tr = targets[bid];
    e_word_h[(long long)bid*E_ + t] = f2bf(emb[(long long)tr*E_ + t]);
    return;
  }
  bid -= 1536;
  if (bid < 256){
    int y = bid >> 7;
    const float* src = y ? Wbw : Wfw;
    unsigned short* dst = WT + (long long)y*2048*256;
    int sid = bid & 127;
    wtr_tile256(src, dst, 2048, 2048, 256, (sid & 31)*64, (sid >> 5)*64, tile);
    return;
  }
  bid -= 256;
  if (bid < 128){ hex[bid*256 + t] = 0u; return; }
  bid -= 128;
  if (bid < 7){
    int i = bid*256 + t;
    if (i < NROW + 1) rowsum[i] = 0.f;
    return;
  }
  bid -= 7;
  int i = bid*256 + t;                       // 16 blocks, 4096 floats
  wsb[i] = (i < 2048) ? bfw[i] : bbw[i - 2048];
}

// ---------------------------------------------------------------------------
// 128x128 bf16 MFMA K-loop, BK=64 (shared by k_bgemm and k_mega).
// ---------------------------------------------------------------------------
__device__ __forceinline__ void gemm128(const unsigned short* __restrict__ Ah,
                                        const unsigned short* __restrict__ Bh,
                                        int K, int m0, int n0,
                                        unsigned short* As, unsigned short* Bs,
                                        f32x4 (&acc)[4][4])
{
  const int t = threadIdx.x;
  const int lane = t & 63, w = t >> 6;
  const int wm = (w >> 1)*64, wn = (w & 1)*64;
  for (int k0 = 0; k0 < K; k0 += 64){
    #pragma unroll
    for (int p = 0; p < 4; p++){
      int rowA = p*32 + (t >> 3);            // 8 threads/row
      int kc = (t & 7) ^ (rowA & 7);
      const unsigned short* ga = Ah + (long long)(m0 + rowA)*K + k0 + kc*8;
      const unsigned short* gb = Bh + (long long)(n0 + rowA)*K + k0 + kc*8;
      unsigned short* la = As + p*2048 + w*512;
      unsigned short* lb = Bs + p*2048 + w*512;
      ASYNC16(ga, la);
      ASYNC16(gb, lb);
    }
    __syncthreads();
    const int rr = lane & 15, kch = lane >> 4;
    #pragma unroll
    for (int kk = 0; kk < 2; kk++){
      short8 af[4], bf[4];
      #pragma unroll
      for (int mi = 0; mi < 4; mi++){
        int rowA = wm + mi*16 + rr;
        int slot = (kk*4 + kch) ^ (rowA & 7);
        af[mi] = *(const short8*)&As[rowA*64 + slot*8];
      }
      #pragma unroll
      for (int ni = 0; ni < 4; ni++){
        int rowB = wn + ni*16 + rr;
        int slot = (kk*4 + kch) ^ (rowB & 7);
        bf[ni] = *(const short8*)&Bs[rowB*64 + slot*8];
      }
      #pragma unroll
      for (int mi = 0; mi < 4; mi++)
        #pragma unroll
        for (int ni = 0; ni < 4; ni++)
          acc[mi][ni] = __builtin_amdgcn_mfma_f32_16x16x32_bf16(af[mi], bf[ni], acc[mi][ni], 0, 0, 0);
    }
    __syncthreads();
  }
}

// Generic bf16 MFMA GEMM (BT layout). MODE 0: Cf=acc+bias; MODE 2: Ch=bf16(tanh(acc+bias)).
template<int MODE>
__global__ __launch_bounds__(256, 2) void k_bgemm(
    const unsigned short* __restrict__ Ah,
    const unsigned short* __restrict__ Bh,
    int K, int ncols,
    const float* __restrict__ bias,
    float* __restrict__ Cf,
    unsigned short* __restrict__ Ch,
    int ldc,
    long long sB2, long long sBias2, long long sC2)
{
  __shared__ unsigned short As[128*64];
  __shared__ unsigned short Bs[128*64];
  if (blockIdx.y){
    Bh += sB2;
    if (bias) bias += sBias2;
    if (Cf) Cf += sC2;
    if (Ch) Ch += sC2;
  }
  int nwg = gridDim.x;
  int braw = blockIdx.x;
  int wg = (braw & 7)*(nwg >> 3) + (braw >> 3);   // bijective: nwg % 8 == 0
  int mt = wg % 12, nt = wg / 12;
  const int m0 = mt*128, n0 = nt*128;
  f32x4 acc[4][4] = {};
  gemm128(Ah, Bh, K, m0, n0, As, Bs, acc);
  const int t = threadIdx.x;
  const int lane = t & 63, w = t >> 6;
  const int wm = (w >> 1)*64, wn = (w & 1)*64;
  #pragma unroll
  for (int mi = 0; mi < 4; mi++){
    #pragma unroll
    for (int r = 0; r < 4; r++){
      int row = m0 + wm + mi*16 + ((lane >> 4) << 2) + r;
      #pragma unroll
      for (int ni = 0; ni < 4; ni++){
        int col = n0 + wn + ni*16 + (lane & 15);
        if (col >= ncols) continue;
        float v = acc[mi][ni][r] + (bias ? bias[col] : 0.f);
        if (MODE == 0){ Cf[(long long)row*ldc + col] = v; }
        if (MODE == 2){
          v = tanhf(v);
          if (Cf) Cf[(long long)row*ldc + col] = v;
          Ch[(long long)row*ldc + col] = f2bf(v);
        }
      }
    }
  }
}

// ---------------------------------------------------------------------------
// Fused persistent bi-LSTM (tagged packets, halved fan-in) + side work.
// Blocks 0..31: LSTM, 16/dir, 32 hidden units (128 gate cols), 512 thr.
//   Protocol identical to r8/r10: packet u64 {h pair, tag}; producer atomic
//   store RELAXED/AGENT tag=step+1 parity (step+1)&1; consumer serial-polls
//   ITS OWN A-frag packets for tag==step; one barrier/step; z_s parity-dbuf.
//   B-frags live in 16 VGPR short8s (loaded once from global W); no W LDS.
// Blocks 32+: side tasks: tnp0(1), W_comboT(128), WjT(32), nullrow(63), WvT(4000).
// ---------------------------------------------------------------------------
__global__ __launch_bounds__(512, 1) void k_fused(
    const float* __restrict__ Xfw, const float* __restrict__ Xbw,
    const float* __restrict__ Wfw, const float* __restrict__ Wbw,
    unsigned int* __restrict__ hex32,
    unsigned short* __restrict__ Hcat_h,
    const int* __restrict__ tnull, const float* __restrict__ emb,
    const float* __restrict__ W1, const float* __restrict__ b1,
    const float* __restrict__ Wp, const float* __restrict__ bp,
    const float* __restrict__ Wv, const float* __restrict__ bv,
    unsigned short* __restrict__ WvT,
    float* __restrict__ lognull, float* __restrict__ nullsum,
    float* __restrict__ p0,
    const float* __restrict__ Wl, unsigned short* __restrict__ W_comboT,
    const float* __restrict__ Wj, unsigned short* __restrict__ WjT)
{
  __shared__ __align__(16) float z_s[2][8][16][132];     // 135168 B, parity-dbuf
  const int bid = blockIdx.x;
  const int t = threadIdx.x;                 // 0..511

  if (bid >= 32){
    float* zflat = &z_s[0][0][0][0];
    int sid = bid - 32;
    if (sid == 0){
      float* en  = zflat;
      float* red = zflat + 256;
      if (t < E_) en[t] = emb[(long long)tnull[0]*E_ + t];
      __syncthreads();
      float s = b1[t];
      for (int e = 0; e < E_; e++) s += en[e]*W1[(long long)e*H_ + t];
      red[t] = tanhf(s)*Wp[t];
      __syncthreads();
      for (int w = 256; w > 0; w >>= 1){
        if (t < w) red[t] += red[t+w];
        __syncthreads();
      }
      if (t == 0) p0[0] = sigfast(red[0] + bp[0])*0.3f;
      return;
    }
    sid -= 1;
    if (sid < 128){
      const int K8 = sid*8;
      float* WlS = zflat;            // [8][256]
      #pragma unroll
      for (int rep = 0; rep < 4; rep++){
        int id = rep*512 + t;
        int kl = id >> 8, e = id & 255;
        WlS[kl*256 + e] = Wl[(long long)(K8 + kl)*256 + e];
      }
      __syncthreads();
      float acc[8] = {};
      for (int e = 0; e < 256; e++){
        float w1v = W1[(long long)e*512 + t];
        #pragma unroll
        for (int j = 0; j < 8; j++) acc[j] += WlS[j*256 + e]*w1v;
      }
      #pragma unroll
      for (int j = 0; j < 8; j++)
        W_comboT[(long long)t*1024 + K8 + j] = f2bf(acc[j]);
      return;
    }
    sid -= 128;
    if (sid < 32){
      wtr_tile(Wj, WjT, SJ_, SJ_, 512, (sid & 3)*64, (sid >> 2)*64, zflat);
      return;
    }
    sid -= 32;
    if (sid < 63){
      float* en  = zflat;
      float* tns = zflat + 256;
      float* red = zflat + 768;
      if (t < E_) en[t] = emb[(long long)tnull[0]*E_ + t];
      __syncthreads();
      float s0 = b1[t];
      for (int e = 0; e < E_; e++) s0 += en[e]*W1[(long long)e*H_ + t];
      tns[t] = tanhf(s0);
      __syncthreads();
      int c = sid*512 + t;
      float p = 0.f;
      if (c < VS_){
        float s = bv[c];
        for (int k = 0; k < H_; k++) s += tns[k]*Wv[(long long)k*VS_ + c];
        lognull[c] = s;
        p = __expf(s);
      }
      red[t] = p;
      __syncthreads();
      for (int w = 256; w > 0; w >>= 1){
        if (t < w) red[t] += red[t+w];
        __syncthreads();
      }
      if (t == 0) atomicAdd(nullsum, red[0]);
      return;
    }
    sid -= 63;
    wtr_tile(Wv, WvT, VS_, VS_, H_, (sid % 500)*64, (sid / 500)*64, zflat);
    return;
  }

  // ---------------- LSTM path ----------------
  const int dir = bid >> 4;
  const int slice = bid & 15;
  const int u0 = slice * 32;                 // 32 hidden units per block
  const int lane = t & 63;
  const int w = t >> 6;                      // wave = K-eighth (chunks 2w, 2w+1)
  const int m = lane & 15, hi = lane >> 4;
  const float* X = dir ? Xbw : Xfw;
  const float* Wg = (dir ? Wbw : Wfw) + (long long)E_*2048;
  char* hexd = (char*)hex32 + dir*65536;

  // B-fragments direct from global W (fp32 -> bf16), loop-invariant, in VGPRs.
  // LDS col c (0..127): gate g = c>>5, unit uu = c&31 -> global col g*512+u0+uu.
  short8 bfr[8][2];
  #pragma unroll
  for (int nt = 0; nt < 8; nt++){
    int c = nt*16 + m;
    int gcol = (c >> 5)*512 + u0 + (c & 31);
    #pragma unroll
    for (int ck = 0; ck < 2; ck++){
      int kbase = (2*w + ck)*32 + hi*8;
      union { short s[8]; short8 v; } tmp;
      #pragma unroll
      for (int j = 0; j < 8; j++)
        tmp.s[j] = (short)f2bf(Wg[(long long)(kbase + j)*2048 + gcol]);
      bfr[nt][ck] = tmp.v;
    }
  }

  const int eb = t >> 5, eu = t & 31;        // gate thread: batch eb, unit eu
  float creg = 0.f;

  for (int step = 0; step < J_; step++){
    const int par = step & 1;
    const int t_eff = dir ? (J_-1-step) : step;
    // X prefetch BEFORE poll (fp32, latency hides under the spin)
    const float* xr = X + ((long long)eb*J_ + t_eff)*2048 + u0 + eu;
    float xg0 = xr[0], xg1 = xr[512], xg2 = xr[1024], xg3 = xr[1536];
    asm volatile("" : "+v"(xg0), "+v"(xg1), "+v"(xg2), "+v"(xg3));
    // ---- r8-proven simple poll of own A-frag packets ----
    const char* ap = hexd + par*32768 + m*2048 + w*256 + hi*32;
    u32x4 d0, d1, d2, d3;
    const unsigned expt = (unsigned)step;
    unsigned spin = 0;
    for (;;){
      asm volatile("global_load_dwordx4 %0, %1, off sc0 sc1" : "=v"(d0) : "v"(ap));
      asm volatile("global_load_dwordx4 %0, %1, off offset:16 sc0 sc1" : "=v"(d1) : "v"(ap));
      asm volatile("global_load_dwordx4 %0, %1, off offset:128 sc0 sc1" : "=v"(d2) : "v"(ap));
      asm volatile("global_load_dwordx4 %0, %1, off offset:144 sc0 sc1" : "=v"(d3) : "v"(ap));
      asm volatile("s_waitcnt vmcnt(0)" ::: "memory");
      unsigned bad = (d0[1]^expt)|(d0[3]^expt)|(d1[1]^expt)|(d1[3]^expt)
                   | (d2[1]^expt)|(d2[3]^expt)|(d3[1]^expt)|(d3[3]^expt);
      if (__all(bad == 0u)) break;
      if (++spin > 65536u) break;            // bounded-spin escape (fail clean)
      __builtin_amdgcn_s_sleep(1);
    }
    __builtin_amdgcn_sched_barrier(0);
    // strip tags -> A-frags
    union { unsigned int u[4]; short8 s; } a0, a1;
    a0.u[0]=d0[0]; a0.u[1]=d0[2]; a0.u[2]=d1[0]; a0.u[3]=d1[2];
    a1.u[0]=d2[0]; a1.u[1]=d2[2]; a1.u[2]=d3[0]; a1.u[3]=d3[2];
    f32x4 acc[8] = {};
    #pragma unroll
    for (int nt = 0; nt < 8; nt++){
      acc[nt] = __builtin_amdgcn_mfma_f32_16x16x32_bf16(a0.s, bfr[nt][0], acc[nt], 0,0,0);
      acc[nt] = __builtin_amdgcn_mfma_f32_16x16x32_bf16(a1.s, bfr[nt][1], acc[nt], 0,0,0);
    }
    #pragma unroll
    for (int nt = 0; nt < 8; nt++)
      #pragma unroll
      for (int r = 0; r < 4; r++)
        z_s[par][w][hi*4 + r][nt*16 + m] = acc[nt][r];
    __syncthreads();                  // single barrier per step
    {
      float z0 = xg0, z1 = xg1, z2 = xg2, z3 = xg3;
      #pragma unroll
      for (int ke = 0; ke < 8; ke++){
        z0 += z_s[par][ke][eb][eu];
        z1 += z_s[par][ke][eb][32 + eu];
        z2 += z_s[par][ke][eb][64 + eu];
        z3 += z_s[par][ke][eb][96 + eu];
      }
      creg = sigfast(z2 + 1.f)*creg + sigfast(z0)*tanhfast(z1);
      float hh = sigfast(z3)*tanhfast(creg);
      unsigned int hb16 = (unsigned int)f2bf(hh);
      unsigned int nb = (unsigned int)__shfl_xor((int)hb16, 1);
      if (!(eu & 1)){
        unsigned long long pkt = (unsigned long long)((hb16 & 0xffffu) | (nb << 16))
                               | ((unsigned long long)(unsigned)(step+1) << 32);
        __hip_atomic_store((unsigned long long*)(hexd + (par^1)*32768 + eb*2048 + (u0 + eu)*4),
                           pkt, __ATOMIC_RELAXED, __HIP_MEMORY_SCOPE_AGENT);
      }
      Hcat_h[((long long)eb*J_ + t_eff)*1024 + dir*512 + u0 + eu] = (unsigned short)hb16;
    }
  }
}

// ---------------------------------------------------------------------------
// Mega tail: rowsum GEMM (3000) + jump-logit GEMM (24) + gathered numerators
// ---------------------------------------------------------------------------
__global__ __launch_bounds__(256, 2) void k_mega(
    const unsigned short* __restrict__ t1h,
    const unsigned short* __restrict__ WvT,
    const unsigned short* __restrict__ WjT,
    const float* __restrict__ bv, const float* __restrict__ bj,
    const int* __restrict__ sources,
    float* __restrict__ rowsum, float* __restrict__ jlog,
    float* __restrict__ out_em)
{
  __shared__ unsigned short As[128*64];
  __shared__ unsigned short Bs[128*64];
  const int t = threadIdx.x;
  const int lane = t & 63, w = t >> 6;
  int bid = blockIdx.x;
  if (bid >= 3024){
    int tile = (bid - 3024)*4 + w;            // 0..575
    int b = tile / 36, tl = tile % 36;
    int mt = tl / 6, nt = tl % 6;
    const int rr = lane & 15, kq = lane >> 4;
    int s = sources[b*96 + nt*16 + rr];
    float bg = bv[s];
    const unsigned short* arow = t1h + ((long long)(b*96 + mt*16 + rr))*512 + kq*8;
    const unsigned short* brow = WvT + (long long)s*512 + kq*8;
    f32x4 acc = {0.f,0.f,0.f,0.f};
    #pragma unroll
    for (int kc = 0; kc < 16; kc++){
      short8 af = *(const short8*)(arow + kc*32);
      short8 bf = *(const short8*)(brow + kc*32);
      acc = __builtin_amdgcn_mfma_f32_16x16x32_bf16(af, bf, acc, 0, 0, 0);
    }
    #pragma unroll
    for (int r = 0; r < 4; r++){
      int j = mt*16 + kq*4 + r;
      int i = nt*16 + rr;
      out_em[((long long)b*192 + j)*96 + i] = __expf(acc[r] + bg);
    }
    return;
  }
  const bool isjl = (bid >= 3000);
  int m0, n0;
  const unsigned short* Bh;
  if (isjl){
    int idx = bid - 3000;
    m0 = (idx % 12)*128; n0 = (idx / 12)*128;
    Bh = WjT;
  } else {
    int wg = (bid & 7)*375 + (bid >> 3);
    m0 = (wg % 12)*128; n0 = (wg / 12)*128;
    Bh = WvT;
  }
  f32x4 acc[4][4] = {};
  gemm128(t1h, Bh, H_, m0, n0, As, Bs, acc);
  const int wm = (w >> 1)*64, wn = (w & 1)*64;
  #pragma unroll
  for (int mi = 0; mi < 4; mi++){
    #pragma unroll
    for (int r = 0; r < 4; r++){
      int row = m0 + wm + mi*16 + ((lane >> 4) << 2) + r;
      if (isjl){
        #pragma unroll
        for (int ni = 0; ni < 4; ni++){
          int col = n0 + wn + ni*16 + (lane & 15);
          if (col < SJ_) jlog[(long long)row*SJ_ + col] = acc[mi][ni][r] + bj[col];
        }
      } else {
        float s = 0.f;
        #pragma unroll
        for (int ni = 0; ni < 4; ni++){
          int col = n0 + wn + ni*16 + (lane & 15);
          s += __expf(acc[mi][ni][r] + bv[col]);
        }
        s += __shfl_xor(s, 1);
        s += __shfl_xor(s, 2);
        s += __shfl_xor(s, 4);
        s += __shfl_xor(s, 8);
        if ((lane & 15) == 0) atomicAdd(&rowsum[row], s);
      }
    }
  }
}

// ---------------------------------------------------------------------------
// Final: transition + word-emission divide (blocks 0..1535) + null rows (16).
// ---------------------------------------------------------------------------
__global__ __launch_bounds__(128) void k_final(
    const float* __restrict__ jlog, const float* __restrict__ p0p,
    const float* __restrict__ rowsum,
    const float* __restrict__ lognull, const float* __restrict__ nullsum,
    const int* __restrict__ sources,
    float* __restrict__ out_em, float* __restrict__ T, float* __restrict__ TL)
{
  __shared__ float ex[128];
  __shared__ float red[128];
  int bx = blockIdx.x;
  int tid = threadIdx.x;
  if (bx >= NROW){
    int b = bx - NROW;
    if (tid < 96){
      int s = sources[b*96 + tid];
      float v = __expf(lognull[s]) / nullsum[0];
      for (int jj = 0; jj < 96; jj++)
        out_em[((long long)b*192 + 96 + jj)*96 + tid] = v;
    }
    return;
  }
  int b = bx / J_, j = bx % J_;
  float inv = 1.f / rowsum[bx];
  if (tid < 96)
    out_em[((long long)b*192 + j)*96 + tid] *= inv;
  float e = 0.f;
  if (tid < 96) e = __expf(jlog[(long long)bx*SJ_ + (96 - j + tid)]);
  ex[tid] = e; red[tid] = e;
  __syncthreads();
  for (int w = 64; w > 0; w >>= 1){
    if (tid < w) red[tid] += red[tid+w];
    __syncthreads();
  }
  float p0 = p0p[0];
  float scale = (1.f - p0) / red[0];
  float lp0 = logf(p0);
  long long r0 = ((long long)b*192 + j)*192;
  long long r1 = ((long long)b*192 + j + 96)*192;
  for (int col = tid; col < 192; col += 128){
    float tv, lv;
    if (col < 96){ tv = ex[col]*scale; lv = logf(tv); }
    else { bool d = (col - 96) == j; tv = d ? p0 : 0.f; lv = d ? lp0 : 0.f; }
    T[r0 + col] = tv; T[r1 + col] = tv;
    TL[r0 + col] = lv; TL[r1 + col] = lv;
  }
}

extern "C" void kernel_launch(void* const* d_in, const int* in_sizes, int n_in,
                              void* d_out, int out_size, void* d_ws, size_t ws_size,
                              hipStream_t stream)
{
  const int* sources = (const int*)d_in[0];
  const int* targets = (const int*)d_in[1];
  const int* tnull   = (const int*)d_in[2];
  const float* emb   = (const float*)d_in[3];
  const float* Wfw   = (const float*)d_in[4];
  const float* bfw   = (const float*)d_in[5];
  const float* Wbw   = (const float*)d_in[6];
  const float* bbw   = (const float*)d_in[7];
  const float* Wl    = (const float*)d_in[8];
  const float* W1    = (const float*)d_in[9];
  const float* b1    = (const float*)d_in[10];
  const float* Wv    = (const float*)d_in[11];
  const float* bv    = (const float*)d_in[12];
  const float* Wj    = (const float*)d_in[13];
  const float* bj    = (const float*)d_in[14];
  const float* Wp    = (const float*)d_in[15];
  const float* bp    = (const float*)d_in[16];
  float* out = (float*)d_out;
  float* ws  = (float*)d_ws;

  long long off = 0;
  float* Xfw    = ws + off; off += (long long)NROW*2048;
  float* Xbw    = ws + off; off += (long long)NROW*2048;   // must follow Xfw (sC2)
  unsigned short* e_word_h = (unsigned short*)(ws + off); off += (long long)NROW*E_/2;
  unsigned short* WT       = (unsigned short*)(ws + off); off += 2LL*2048*256/2;
  unsigned short* Hcat_h   = (unsigned short*)(ws + off); off += (long long)NROW*1024/2;
  unsigned int* hex32 = (unsigned int*)(ws + off); off += 32768;
  unsigned short* t1h = (unsigned short*)(ws + off); off += (long long)NROW*H_/2;
  unsigned short* W_comboT = (unsigned short*)(ws + off); off += 512LL*1024/2;
  unsigned short* WjT      = (unsigned short*)(ws + off); off += 256LL*512/2;
  float* rowsum = ws + off; off += NROW;
  float* nullsum= ws + off; off += 1;
  float* p0     = ws + off; off += 1;
  float* wsb    = ws + off; off += 4096;
  float* lognull= ws + off; off += VS_;
  float* jlog   = ws + off; off += (long long)NROW*SJ_;
  unsigned short* WvT = (unsigned short*)(ws + off); off += (long long)VS_*H_/2;

  float* out_em = out;
  float* out_T  = out + (long long)B_*192*96;
  float* out_TL = out_T + (long long)B_*192*192;

  // 1) head: init + embed + W transposes + bias copy
  k_head<<<1943, 256, 0, stream>>>(targets, emb, e_word_h, Wfw, Wbw, WT,
                                   hex32, rowsum, bfw, bbw, wsb);

  // 2) input projections, both dirs in one launch (y selects dir), fp32 out
  k_bgemm<0><<<dim3(192, 2), 256, 0, stream>>>(e_word_h, WT, E_, 2048, wsb,
                                               Xfw, nullptr, 2048,
                                               2048LL*256, 2048LL, (long long)NROW*2048);

  // 3) fused persistent tagged-packet bi-LSTM (32 blocks) + side work
  k_fused<<<4256, 512, 0, stream>>>(Xfw, Xbw, Wfw, Wbw, hex32, Hcat_h,
                                    tnull, emb, W1, b1, Wp, bp, Wv, bv,
                                    WvT, lognull, nullsum, p0,
                                    Wl, W_comboT, Wj, WjT);

  // 4) t1h = bf16(tanh(Hcat @ (Wl@W1) + b1))
  k_bgemm<2><<<dim3(48, 1), 256, 0, stream>>>(Hcat_h, W_comboT, 2*H_, H_, b1,
                                              nullptr, t1h, H_, 0, 0, 0);

  // 5) mega tail: rowsum + jump logits + gathered numerators
  k_mega<<<3168, 256, 0, stream>>>(t1h, WvT, WjT, bv, bj, sources,
                                   rowsum, jlog, out_em);

  // 6) final: transition + emission divide + null rows
  k_final<<<NROW + B_, 128, 0, stream>>>(jlog, p0, rowsum, lognull, nullsum,
                                         sources, out_em, out_T, out_TL);
}

// Round 14
// 394.650 us; speedup vs baseline: 1.4324x; 1.0041x over previous
//
#include <hip/hip_runtime.h>
#include <math.h>

#define B_ 16
#define J_ 96
#define I_ 96
#define E_ 256
#define H_ 512
#define VS_ 32000
#define SJ_ 193
#define NROW (B_*J_)   // 1536

typedef __attribute__((ext_vector_type(8))) short short8;
typedef __attribute__((ext_vector_type(4))) float f32x4;
typedef __attribute__((ext_vector_type(4))) unsigned int u32x4;

__device__ __forceinline__ float rcpfast(float x){
  float r;
  asm volatile("v_rcp_f32 %0, %1" : "=v"(r) : "v"(x));
  return r;
}
__device__ __forceinline__ float sigfast(float x){
  return rcpfast(1.f + __expf(-x));
}
__device__ __forceinline__ float tanhfast(float x){
  float e = __expf(2.f*x);
  return 1.f - 2.f*rcpfast(e + 1.f);     // e=inf -> 1, e=0 -> -1
}

__device__ __forceinline__ unsigned short f2bf(float x){
  unsigned int u = __float_as_uint(x);
  unsigned int r = (u + 0x7FFFu + ((u>>16)&1u)) >> 16;
  return (unsigned short)r;
}

#define ASYNC16(gp, lp) __builtin_amdgcn_global_load_lds( \
    (const __attribute__((address_space(1))) unsigned int*)(gp), \
    (__attribute__((address_space(3))) unsigned int*)(lp), 16, 0, 0)

// 256-thr transpose+convert: src fp32 [K][ld] -> dst bf16 [N][K], zero-pad n>=nmax
__device__ __forceinline__ void wtr_tile256(const float* __restrict__ src,
                                            unsigned short* __restrict__ dst,
                                            int ldN, int nmax, int K, int n0, int k0,
                                            float* __restrict__ tile /*[64][65]*/)
{
  const int t = threadIdx.x;
  #pragma unroll
  for (int rep = 0; rep < 16; rep++){
    int idx = rep*256 + t;
    int kk = idx >> 6, nn = idx & 63;
    tile[kk*65 + nn] = (n0+nn < nmax) ? src[(long long)(k0+kk)*ldN + n0 + nn] : 0.f;
  }
  __syncthreads();
  #pragma unroll
  for (int rep = 0; rep < 16; rep++){
    int idx = rep*256 + t;
    int nn = idx >> 6, kk = idx & 63;
    dst[(long long)(n0+nn)*K + k0 + kk] = f2bf(tile[kk*65 + nn]);
  }
}

// 512-thr version (used in k_fused side tasks)
__device__ __forceinline__ void wtr_tile(const float* __restrict__ src,
                                         unsigned short* __restrict__ dst,
                                         int ldN, int nmax, int K, int n0, int k0,
                                         float* __restrict__ tile)
{
  const int t = threadIdx.x;
  #pragma unroll
  for (int rep = 0; rep < 8; rep++){
    int idx = rep*512 + t;
    int kk = idx >> 6, nn = idx & 63;
    tile[kk*65 + nn] = (n0+nn < nmax) ? src[(long long)(k0+kk)*ldN + n0 + nn] : 0.f;
  }
  __syncthreads();
  #pragma unroll
  for (int rep = 0; rep < 8; rep++){
    int idx = rep*512 + t;
    int nn = idx >> 6, kk = idx & 63;
    dst[(long long)(n0+nn)*K + k0 + kk] = f2bf(tile[kk*65 + nn]);
  }
}

// ---------------------------------------------------------------------------
// Head: init hex/rowsum, embed->bf16, Wfw/Wbw transpose, bias copy. One launch.
// ---------------------------------------------------------------------------
__global__ __launch_bounds__(256) void k_head(
    const int* __restrict__ targets, const float* __restrict__ emb,
    unsigned short* __restrict__ e_word_h,
    const float* __restrict__ Wfw, const float* __restrict__ Wbw,
    unsigned short* __restrict__ WT,
    unsigned int* __restrict__ hex, float* __restrict__ rowsum,
    const float* __restrict__ bfw, const float* __restrict__ bbw,
    float* __restrict__ wsb)
{
  __shared__ float tile[64*65];
  int bid = blockIdx.x;
  const int t = threadIdx.x;
  if (bid < 1536){
    int tr = targets[bid];
    e_word_h[(long long)bid*E_ + t] = f2bf(emb[(long long)tr*E_ + t]);
    return;
  }
  bid -= 1536;
  if (bid < 256){
    int y = bid >> 7;
    const float* src = y ? Wbw : Wfw;
    unsigned short* dst = WT + (long long)y*2048*256;
    int sid = bid & 127;
    wtr_tile256(src, dst, 2048, 2048, 256, (sid & 31)*64, (sid >> 5)*64, tile);
    return;
  }
  bid -= 256;
  if (bid < 128){ hex[bid*256 + t] = 0u; return; }
  bid -= 128;
  if (bid < 7){
    int i = bid*256 + t;
    if (i < NROW + 1) rowsum[i] = 0.f;
    return;
  }
  bid -= 7;
  int i = bid*256 + t;                       // 16 blocks, 4096 floats
  wsb[i] = (i < 2048) ? bfw[i] : bbw[i - 2048];
}

// ---------------------------------------------------------------------------
// 128x128 bf16 MFMA K-loop, BK=64 (shared by k_bgemm and k_mega).
// ---------------------------------------------------------------------------
__device__ __forceinline__ void gemm128(const unsigned short* __restrict__ Ah,
                                        const unsigned short* __restrict__ Bh,
                                        int K, int m0, int n0,
                                        unsigned short* As, unsigned short* Bs,
                                        f32x4 (&acc)[4][4])
{
  const int t = threadIdx.x;
  const int lane = t & 63, w = t >> 6;
  const int wm = (w >> 1)*64, wn = (w & 1)*64;
  for (int k0 = 0; k0 < K; k0 += 64){
    #pragma unroll
    for (int p = 0; p < 4; p++){
      int rowA = p*32 + (t >> 3);            // 8 threads/row
      int kc = (t & 7) ^ (rowA & 7);
      const unsigned short* ga = Ah + (long long)(m0 + rowA)*K + k0 + kc*8;
      const unsigned short* gb = Bh + (long long)(n0 + rowA)*K + k0 + kc*8;
      unsigned short* la = As + p*2048 + w*512;
      unsigned short* lb = Bs + p*2048 + w*512;
      ASYNC16(ga, la);
      ASYNC16(gb, lb);
    }
    __syncthreads();
    const int rr = lane & 15, kch = lane >> 4;
    #pragma unroll
    for (int kk = 0; kk < 2; kk++){
      short8 af[4], bf[4];
      #pragma unroll
      for (int mi = 0; mi < 4; mi++){
        int rowA = wm + mi*16 + rr;
        int slot = (kk*4 + kch) ^ (rowA & 7);
        af[mi] = *(const short8*)&As[rowA*64 + slot*8];
      }
      #pragma unroll
      for (int ni = 0; ni < 4; ni++){
        int rowB = wn + ni*16 + rr;
        int slot = (kk*4 + kch) ^ (rowB & 7);
        bf[ni] = *(const short8*)&Bs[rowB*64 + slot*8];
      }
      #pragma unroll
      for (int mi = 0; mi < 4; mi++)
        #pragma unroll
        for (int ni = 0; ni < 4; ni++)
          acc[mi][ni] = __builtin_amdgcn_mfma_f32_16x16x32_bf16(af[mi], bf[ni], acc[mi][ni], 0, 0, 0);
    }
    __syncthreads();
  }
}

// Generic bf16 MFMA GEMM (BT layout). MODE 0: Cf=acc+bias; MODE 2: Ch=bf16(tanh(acc+bias)).
template<int MODE>
__global__ __launch_bounds__(256, 2) void k_bgemm(
    const unsigned short* __restrict__ Ah,
    const unsigned short* __restrict__ Bh,
    int K, int ncols,
    const float* __restrict__ bias,
    float* __restrict__ Cf,
    unsigned short* __restrict__ Ch,
    int ldc,
    long long sB2, long long sBias2, long long sC2)
{
  __shared__ unsigned short As[128*64];
  __shared__ unsigned short Bs[128*64];
  if (blockIdx.y){
    Bh += sB2;
    if (bias) bias += sBias2;
    if (Cf) Cf += sC2;
    if (Ch) Ch += sC2;
  }
  int nwg = gridDim.x;
  int braw = blockIdx.x;
  int wg = (braw & 7)*(nwg >> 3) + (braw >> 3);   // bijective: nwg % 8 == 0
  int mt = wg % 12, nt = wg / 12;
  const int m0 = mt*128, n0 = nt*128;
  f32x4 acc[4][4] = {};
  gemm128(Ah, Bh, K, m0, n0, As, Bs, acc);
  const int t = threadIdx.x;
  const int lane = t & 63, w = t >> 6;
  const int wm = (w >> 1)*64, wn = (w & 1)*64;
  #pragma unroll
  for (int mi = 0; mi < 4; mi++){
    #pragma unroll
    for (int r = 0; r < 4; r++){
      int row = m0 + wm + mi*16 + ((lane >> 4) << 2) + r;
      #pragma unroll
      for (int ni = 0; ni < 4; ni++){
        int col = n0 + wn + ni*16 + (lane & 15);
        if (col >= ncols) continue;
        float v = acc[mi][ni][r] + (bias ? bias[col] : 0.f);
        if (MODE == 0){ Cf[(long long)row*ldc + col] = v; }
        if (MODE == 2){
          v = tanhf(v);
          if (Cf) Cf[(long long)row*ldc + col] = v;
          Ch[(long long)row*ldc + col] = f2bf(v);
        }
      }
    }
  }
}

// ---------------------------------------------------------------------------
// Fused persistent bi-LSTM (tagged packets, r12-proven: 32 blocks, 16/dir x
// 32 units) + side work. 512 thr = 8 waves = 8 K-eighths.
//   Packet u64 {h pair, tag}; producer atomic store RELAXED/AGENT tag=step+1
//   parity (step+1)&1; consumer serial-polls ITS OWN A-frag packets for
//   tag==step; one barrier/step; z_s parity-dbuf. B-frags in 16 VGPR short8s.
// Blocks 32+: side tasks: tnp0(1), W_comboT(128), WjT(32), nullrow(63), WvT(4000).
// ---------------------------------------------------------------------------
__global__ __launch_bounds__(512, 1) void k_fused(
    const float* __restrict__ Xfw, const float* __restrict__ Xbw,
    const float* __restrict__ Wfw, const float* __restrict__ Wbw,
    unsigned int* __restrict__ hex32,
    unsigned short* __restrict__ Hcat_h,
    const int* __restrict__ tnull, const float* __restrict__ emb,
    const float* __restrict__ W1, const float* __restrict__ b1,
    const float* __restrict__ Wp, const float* __restrict__ bp,
    const float* __restrict__ Wv, const float* __restrict__ bv,
    unsigned short* __restrict__ WvT,
    float* __restrict__ lognull, float* __restrict__ nullsum,
    float* __restrict__ p0,
    const float* __restrict__ Wl, unsigned short* __restrict__ W_comboT,
    const float* __restrict__ Wj, unsigned short* __restrict__ WjT)
{
  __shared__ __align__(16) float z_s[2][8][16][132];     // 135168 B, parity-dbuf
  const int bid = blockIdx.x;
  const int t = threadIdx.x;                 // 0..511

  if (bid >= 32){
    float* zflat = &z_s[0][0][0][0];
    int sid = bid - 32;
    if (sid == 0){
      float* en  = zflat;
      float* red = zflat + 256;
      if (t < E_) en[t] = emb[(long long)tnull[0]*E_ + t];
      __syncthreads();
      float s = b1[t];
      for (int e = 0; e < E_; e++) s += en[e]*W1[(long long)e*H_ + t];
      red[t] = tanhf(s)*Wp[t];
      __syncthreads();
      for (int w = 256; w > 0; w >>= 1){
        if (t < w) red[t] += red[t+w];
        __syncthreads();
      }
      if (t == 0) p0[0] = sigfast(red[0] + bp[0])*0.3f;
      return;
    }
    sid -= 1;
    if (sid < 128){
      const int K8 = sid*8;
      float* WlS = zflat;            // [8][256]
      #pragma unroll
      for (int rep = 0; rep < 4; rep++){
        int id = rep*512 + t;
        int kl = id >> 8, e = id & 255;
        WlS[kl*256 + e] = Wl[(long long)(K8 + kl)*256 + e];
      }
      __syncthreads();
      float acc[8] = {};
      for (int e = 0; e < 256; e++){
        float w1v = W1[(long long)e*512 + t];
        #pragma unroll
        for (int j = 0; j < 8; j++) acc[j] += WlS[j*256 + e]*w1v;
      }
      #pragma unroll
      for (int j = 0; j < 8; j++)
        W_comboT[(long long)t*1024 + K8 + j] = f2bf(acc[j]);
      return;
    }
    sid -= 128;
    if (sid < 32){
      wtr_tile(Wj, WjT, SJ_, SJ_, 512, (sid & 3)*64, (sid >> 2)*64, zflat);
      return;
    }
    sid -= 32;
    if (sid < 63){
      float* en  = zflat;
      float* tns = zflat + 256;
      float* red = zflat + 768;
      if (t < E_) en[t] = emb[(long long)tnull[0]*E_ + t];
      __syncthreads();
      float s0 = b1[t];
      for (int e = 0; e < E_; e++) s0 += en[e]*W1[(long long)e*H_ + t];
      tns[t] = tanhf(s0);
      __syncthreads();
      int c = sid*512 + t;
      float p = 0.f;
      if (c < VS_){
        float s = bv[c];
        for (int k = 0; k < H_; k++) s += tns[k]*Wv[(long long)k*VS_ + c];
        lognull[c] = s;
        p = __expf(s);
      }
      red[t] = p;
      __syncthreads();
      for (int w = 256; w > 0; w >>= 1){
        if (t < w) red[t] += red[t+w];
        __syncthreads();
      }
      if (t == 0) atomicAdd(nullsum, red[0]);
      return;
    }
    sid -= 63;
    wtr_tile(Wv, WvT, VS_, VS_, H_, (sid % 500)*64, (sid / 500)*64, zflat);
    return;
  }

  // ---------------- LSTM path ----------------
  const int dir = bid >> 4;
  const int slice = bid & 15;
  const int u0 = slice * 32;                 // 32 hidden units per block
  const int lane = t & 63;
  const int w = t >> 6;                      // wave = K-eighth (chunks 2w, 2w+1)
  const int m = lane & 15, hi = lane >> 4;
  const float* X = dir ? Xbw : Xfw;
  const float* Wg = (dir ? Wbw : Wfw) + (long long)E_*2048;
  char* hexd = (char*)hex32 + dir*65536;

  // B-fragments direct from global W (fp32 -> bf16), loop-invariant, in VGPRs.
  // LDS col c (0..127): gate g = c>>5, unit uu = c&31 -> global col g*512+u0+uu.
  short8 bfr[8][2];
  #pragma unroll
  for (int nt = 0; nt < 8; nt++){
    int c = nt*16 + m;
    int gcol = (c >> 5)*512 + u0 + (c & 31);
    #pragma unroll
    for (int ck = 0; ck < 2; ck++){
      int kbase = (2*w + ck)*32 + hi*8;
      union { short s[8]; short8 v; } tmp;
      #pragma unroll
      for (int j = 0; j < 8; j++)
        tmp.s[j] = (short)f2bf(Wg[(long long)(kbase + j)*2048 + gcol]);
      bfr[nt][ck] = tmp.v;
    }
  }

  const int eb = t >> 5, eu = t & 31;        // gate thread: batch eb, unit eu
  float creg = 0.f;

  for (int step = 0; step < J_; step++){
    const int par = step & 1;
    const int t_eff = dir ? (J_-1-step) : step;
    // X prefetch BEFORE poll (fp32, latency hides under the spin)
    const float* xr = X + ((long long)eb*J_ + t_eff)*2048 + u0 + eu;
    float xg0 = xr[0], xg1 = xr[512], xg2 = xr[1024], xg3 = xr[1536];
    asm volatile("" : "+v"(xg0), "+v"(xg1), "+v"(xg2), "+v"(xg3));
    // ---- r8-proven simple poll of own A-frag packets ----
    const char* ap = hexd + par*32768 + m*2048 + w*256 + hi*32;
    u32x4 d0, d1, d2, d3;
    const unsigned expt = (unsigned)step;
    unsigned spin = 0;
    for (;;){
      asm volatile("global_load_dwordx4 %0, %1, off sc0 sc1" : "=v"(d0) : "v"(ap));
      asm volatile("global_load_dwordx4 %0, %1, off offset:16 sc0 sc1" : "=v"(d1) : "v"(ap));
      asm volatile("global_load_dwordx4 %0, %1, off offset:128 sc0 sc1" : "=v"(d2) : "v"(ap));
      asm volatile("global_load_dwordx4 %0, %1, off offset:144 sc0 sc1" : "=v"(d3) : "v"(ap));
      asm volatile("s_waitcnt vmcnt(0)" ::: "memory");
      unsigned bad = (d0[1]^expt)|(d0[3]^expt)|(d1[1]^expt)|(d1[3]^expt)
                   | (d2[1]^expt)|(d2[3]^expt)|(d3[1]^expt)|(d3[3]^expt);
      if (__all(bad == 0u)) break;
      if (++spin > 65536u) break;            // bounded-spin escape (fail clean)
      __builtin_amdgcn_s_sleep(1);
    }
    __builtin_amdgcn_sched_barrier(0);
    // strip tags -> A-frags
    union { unsigned int u[4]; short8 s; } a0, a1;
    a0.u[0]=d0[0]; a0.u[1]=d0[2]; a0.u[2]=d1[0]; a0.u[3]=d1[2];
    a1.u[0]=d2[0]; a1.u[1]=d2[2]; a1.u[2]=d3[0]; a1.u[3]=d3[2];
    f32x4 acc[8] = {};
    #pragma unroll
    for (int nt = 0; nt < 8; nt++){
      acc[nt] = __builtin_amdgcn_mfma_f32_16x16x32_bf16(a0.s, bfr[nt][0], acc[nt], 0,0,0);
      acc[nt] = __builtin_amdgcn_mfma_f32_16x16x32_bf16(a1.s, bfr[nt][1], acc[nt], 0,0,0);
    }
    #pragma unroll
    for (int nt = 0; nt < 8; nt++)
      #pragma unroll
      for (int r = 0; r < 4; r++)
        z_s[par][w][hi*4 + r][nt*16 + m] = acc[nt][r];
    __syncthreads();                  // single barrier per step
    {
      float z0 = xg0, z1 = xg1, z2 = xg2, z3 = xg3;
      #pragma unroll
      for (int ke = 0; ke < 8; ke++){
        z0 += z_s[par][ke][eb][eu];
        z1 += z_s[par][ke][eb][32 + eu];
        z2 += z_s[par][ke][eb][64 + eu];
        z3 += z_s[par][ke][eb][96 + eu];
      }
      creg = sigfast(z2 + 1.f)*creg + sigfast(z0)*tanhfast(z1);
      float hh = sigfast(z3)*tanhfast(creg);
      unsigned int hb16 = (unsigned int)f2bf(hh);
      unsigned int nb = (unsigned int)__shfl_xor((int)hb16, 1);
      if (!(eu & 1)){
        unsigned long long pkt = (unsigned long long)((hb16 & 0xffffu) | (nb << 16))
                               | ((unsigned long long)(unsigned)(step+1) << 32);
        __hip_atomic_store((unsigned long long*)(hexd + (par^1)*32768 + eb*2048 + (u0 + eu)*4),
                           pkt, __ATOMIC_RELAXED, __HIP_MEMORY_SCOPE_AGENT);
      }
      Hcat_h[((long long)eb*J_ + t_eff)*1024 + dir*512 + u0 + eu] = (unsigned short)hb16;
    }
  }
}

// ---------------------------------------------------------------------------
// Mega tail: rowsum GEMM (3000) + jump-logit GEMM (24) + gathered numerators
// ---------------------------------------------------------------------------
__global__ __launch_bounds__(256, 2) void k_mega(
    const unsigned short* __restrict__ t1h,
    const unsigned short* __restrict__ WvT,
    const unsigned short* __restrict__ WjT,
    const float* __restrict__ bv, const float* __restrict__ bj,
    const int* __restrict__ sources,
    float* __restrict__ rowsum, float* __restrict__ jlog,
    float* __restrict__ out_em)
{
  __shared__ unsigned short As[128*64];
  __shared__ unsigned short Bs[128*64];
  const int t = threadIdx.x;
  const int lane = t & 63, w = t >> 6;
  int bid = blockIdx.x;
  if (bid >= 3024){
    int tile = (bid - 3024)*4 + w;            // 0..575
    int b = tile / 36, tl = tile % 36;
    int mt = tl / 6, nt = tl % 6;
    const int rr = lane & 15, kq = lane >> 4;
    int s = sources[b*96 + nt*16 + rr];
    float bg = bv[s];
    const unsigned short* arow = t1h + ((long long)(b*96 + mt*16 + rr))*512 + kq*8;
    const unsigned short* brow = WvT + (long long)s*512 + kq*8;
    f32x4 acc = {0.f,0.f,0.f,0.f};
    #pragma unroll
    for (int kc = 0; kc < 16; kc++){
      short8 af = *(const short8*)(arow + kc*32);
      short8 bf = *(const short8*)(brow + kc*32);
      acc = __builtin_amdgcn_mfma_f32_16x16x32_bf16(af, bf, acc, 0, 0, 0);
    }
    #pragma unroll
    for (int r = 0; r < 4; r++){
      int j = mt*16 + kq*4 + r;
      int i = nt*16 + rr;
      out_em[((long long)b*192 + j)*96 + i] = __expf(acc[r] + bg);
    }
    return;
  }
  const bool isjl = (bid >= 3000);
  int m0, n0;
  const unsigned short* Bh;
  if (isjl){
    int idx = bid - 3000;
    m0 = (idx % 12)*128; n0 = (idx / 12)*128;
    Bh = WjT;
  } else {
    int wg = (bid & 7)*375 + (bid >> 3);
    m0 = (wg % 12)*128; n0 = (wg / 12)*128;
    Bh = WvT;
  }
  f32x4 acc[4][4] = {};
  gemm128(t1h, Bh, H_, m0, n0, As, Bs, acc);
  const int wm = (w >> 1)*64, wn = (w & 1)*64;
  #pragma unroll
  for (int mi = 0; mi < 4; mi++){
    #pragma unroll
    for (int r = 0; r < 4; r++){
      int row = m0 + wm + mi*16 + ((lane >> 4) << 2) + r;
      if (isjl){
        #pragma unroll
        for (int ni = 0; ni < 4; ni++){
          int col = n0 + wn + ni*16 + (lane & 15);
          if (col < SJ_) jlog[(long long)row*SJ_ + col] = acc[mi][ni][r] + bj[col];
        }
      } else {
        float s = 0.f;
        #pragma unroll
        for (int ni = 0; ni < 4; ni++){
          int col = n0 + wn + ni*16 + (lane & 15);
          s += __expf(acc[mi][ni][r] + bv[col]);
        }
        s += __shfl_xor(s, 1);
        s += __shfl_xor(s, 2);
        s += __shfl_xor(s, 4);
        s += __shfl_xor(s, 8);
        if ((lane & 15) == 0) atomicAdd(&rowsum[row], s);
      }
    }
  }
}

// ---------------------------------------------------------------------------
// Final: transition + word-emission divide (blocks 0..1535) + null rows (16).
// ---------------------------------------------------------------------------
__global__ __launch_bounds__(128) void k_final(
    const float* __restrict__ jlog, const float* __restrict__ p0p,
    const float* __restrict__ rowsum,
    const float* __restrict__ lognull, const float* __restrict__ nullsum,
    const int* __restrict__ sources,
    float* __restrict__ out_em, float* __restrict__ T, float* __restrict__ TL)
{
  __shared__ float ex[128];
  __shared__ float red[128];
  int bx = blockIdx.x;
  int tid = threadIdx.x;
  if (bx >= NROW){
    int b = bx - NROW;
    if (tid < 96){
      int s = sources[b*96 + tid];
      float v = __expf(lognull[s]) / nullsum[0];
      for (int jj = 0; jj < 96; jj++)
        out_em[((long long)b*192 + 96 + jj)*96 + tid] = v;
    }
    return;
  }
  int b = bx / J_, j = bx % J_;
  float inv = 1.f / rowsum[bx];
  if (tid < 96)
    out_em[((long long)b*192 + j)*96 + tid] *= inv;
  float e = 0.f;
  if (tid < 96) e = __expf(jlog[(long long)bx*SJ_ + (96 - j + tid)]);
  ex[tid] = e; red[tid] = e;
  __syncthreads();
  for (int w = 64; w > 0; w >>= 1){
    if (tid < w) red[tid] += red[tid+w];
    __syncthreads();
  }
  float p0 = p0p[0];
  float scale = (1.f - p0) / red[0];
  float lp0 = logf(p0);
  long long r0 = ((long long)b*192 + j)*192;
  long long r1 = ((long long)b*192 + j + 96)*192;
  for (int col = tid; col < 192; col += 128){
    float tv, lv;
    if (col < 96){ tv = ex[col]*scale; lv = logf(tv); }
    else { bool d = (col - 96) == j; tv = d ? p0 : 0.f; lv = d ? lp0 : 0.f; }
    T[r0 + col] = tv; T[r1 + col] = tv;
    TL[r0 + col] = lv; TL[r1 + col] = lv;
  }
}

extern "C" void kernel_launch(void* const* d_in, const int* in_sizes, int n_in,
                              void* d_out, int out_size, void* d_ws, size_t ws_size,
                              hipStream_t stream)
{
  const int* sources = (const int*)d_in[0];
  const int* targets = (const int*)d_in[1];
  const int* tnull   = (const int*)d_in[2];
  const float* emb   = (const float*)d_in[3];
  const float* Wfw   = (const float*)d_in[4];
  const float* bfw   = (const float*)d_in[5];
  const float* Wbw   = (const float*)d_in[6];
  const float* bbw   = (const float*)d_in[7];
  const float* Wl    = (const float*)d_in[8];
  const float* W1    = (const float*)d_in[9];
  const float* b1    = (const float*)d_in[10];
  const float* Wv    = (const float*)d_in[11];
  const float* bv    = (const float*)d_in[12];
  const float* Wj    = (const float*)d_in[13];
  const float* bj    = (const float*)d_in[14];
  const float* Wp    = (const float*)d_in[15];
  const float* bp    = (const float*)d_in[16];
  float* out = (float*)d_out;
  float* ws  = (float*)d_ws;

  long long off = 0;
  float* Xfw    = ws + off; off += (long long)NROW*2048;
  float* Xbw    = ws + off; off += (long long)NROW*2048;   // must follow Xfw (sC2)
  unsigned short* e_word_h = (unsigned short*)(ws + off); off += (long long)NROW*E_/2;
  unsigned short* WT       = (unsigned short*)(ws + off); off += 2LL*2048*256/2;
  unsigned short* Hcat_h   = (unsigned short*)(ws + off); off += (long long)NROW*1024/2;
  unsigned int* hex32 = (unsigned int*)(ws + off); off += 32768;
  unsigned short* t1h = (unsigned short*)(ws + off); off += (long long)NROW*H_/2;
  unsigned short* W_comboT = (unsigned short*)(ws + off); off += 512LL*1024/2;
  unsigned short* WjT      = (unsigned short*)(ws + off); off += 256LL*512/2;
  float* rowsum = ws + off; off += NROW;
  float* nullsum= ws + off; off += 1;
  float* p0     = ws + off; off += 1;
  float* wsb    = ws + off; off += 4096;
  float* lognull= ws + off; off += VS_;
  float* jlog   = ws + off; off += (long long)NROW*SJ_;
  unsigned short* WvT = (unsigned short*)(ws + off); off += (long long)VS_*H_/2;

  float* out_em = out;
  float* out_T  = out + (long long)B_*192*96;
  float* out_TL = out_T + (long long)B_*192*192;

  // 1) head: init + embed + W transposes + bias copy
  k_head<<<1943, 256, 0, stream>>>(targets, emb, e_word_h, Wfw, Wbw, WT,
                                   hex32, rowsum, bfw, bbw, wsb);

  // 2) input projections, both dirs in one launch (y selects dir), fp32 out
  k_bgemm<0><<<dim3(192, 2), 256, 0, stream>>>(e_word_h, WT, E_, 2048, wsb,
                                               Xfw, nullptr, 2048,
                                               2048LL*256, 2048LL, (long long)NROW*2048);

  // 3) fused persistent tagged-packet bi-LSTM (32 blocks) + side work
  k_fused<<<4256, 512, 0, stream>>>(Xfw, Xbw, Wfw, Wbw, hex32, Hcat_h,
                                    tnull, emb, W1, b1, Wp, bp, Wv, bv,
                                    WvT, lognull, nullsum, p0,
                                    Wl, W_comboT, Wj, WjT);

  // 4) t1h = bf16(tanh(Hcat @ (Wl@W1) + b1))
  k_bgemm<2><<<dim3(48, 1), 256, 0, stream>>>(Hcat_h, W_comboT, 2*H_, H_, b1,
                                              nullptr, t1h, H_, 0, 0, 0);

  // 5) mega tail: rowsum + jump logits + gathered numerators
  k_mega<<<3168, 256, 0, stream>>>(t1h, WvT, WjT, bv, bj, sources,
                                   rowsum, jlog, out_em);

  // 6) final: transition + emission divide + null rows
  k_final<<<NROW + B_, 128, 0, stream>>>(jlog, p0, rowsum, lognull, nullsum,
                                         sources, out_em, out_T, out_TL);
}